// Round 1
// baseline (1926.423 us; speedup 1.0000x reference)
//
#include <hip/hip_runtime.h>
#include <hip/hip_bf16.h>

#define B_  4
#define S_  2048
#define D_  1024
#define NH_ 16
#define HD_ 64

// ---------------------------------------------------------------------------
// GEMM: C[m,n] = sum_k A[m,k] * W[n,k]   (A: [M][K], W: [N][K], C: [M][N])
// 64x64 tile, BK=16, 256 threads, each thread 4x4 micro-tile. All f32.
// ---------------------------------------------------------------------------
__global__ __launch_bounds__(256) void gemm_bt_f32(const float* __restrict__ A,
                                                   const float* __restrict__ W,
                                                   float* __restrict__ C,
                                                   int M, int N, int K) {
    const int BM = 64, BN = 64, BK = 16;
    __shared__ float As[16][64 + 4];   // [k][m]
    __shared__ float Ws[16][64 + 4];   // [k][n]
    const int tid = threadIdx.x;
    const int tx = tid & 15;
    const int ty = tid >> 4;
    const int m0 = blockIdx.y * BM;
    const int n0 = blockIdx.x * BN;
    const int lr = tid >> 2;          // 0..63 : row within tile
    const int lk = (tid & 3) << 2;    // 0,4,8,12 : k offset

    float acc[4][4] = {};

    for (int k0 = 0; k0 < K; k0 += BK) {
        float4 a4 = *reinterpret_cast<const float4*>(&A[(size_t)(m0 + lr) * K + k0 + lk]);
        float4 w4 = *reinterpret_cast<const float4*>(&W[(size_t)(n0 + lr) * K + k0 + lk]);
        As[lk + 0][lr] = a4.x; As[lk + 1][lr] = a4.y;
        As[lk + 2][lr] = a4.z; As[lk + 3][lr] = a4.w;
        Ws[lk + 0][lr] = w4.x; Ws[lk + 1][lr] = w4.y;
        Ws[lk + 2][lr] = w4.z; Ws[lk + 3][lr] = w4.w;
        __syncthreads();
#pragma unroll
        for (int k = 0; k < BK; ++k) {
            float4 av = *reinterpret_cast<const float4*>(&As[k][ty * 4]);
            float4 wv = *reinterpret_cast<const float4*>(&Ws[k][tx * 4]);
            float ar[4] = {av.x, av.y, av.z, av.w};
            float wr[4] = {wv.x, wv.y, wv.z, wv.w};
#pragma unroll
            for (int i = 0; i < 4; ++i)
#pragma unroll
                for (int j = 0; j < 4; ++j)
                    acc[i][j] = fmaf(ar[i], wr[j], acc[i][j]);
        }
        __syncthreads();
    }
#pragma unroll
    for (int i = 0; i < 4; ++i) {
        float4 o = make_float4(acc[i][0], acc[i][1], acc[i][2], acc[i][3]);
        *reinterpret_cast<float4*>(&C[(size_t)(m0 + ty * 4 + i) * N + n0 + tx * 4]) = o;
    }
}

// ---------------------------------------------------------------------------
// Flash-attention (f32). One block = one (b, h, 64-row Q tile).
// Streams 64-key tiles of K/V through LDS with online softmax.
// Q/K/V/Y layout: [B][S][D] with head h occupying columns [h*64, h*64+64).
// ---------------------------------------------------------------------------
__global__ __launch_bounds__(256) void attn_f32(const float* __restrict__ Q,
                                                const float* __restrict__ Km,
                                                const float* __restrict__ V,
                                                float* __restrict__ Y) {
    const int qt = blockIdx.x;           // q-tile index (S/64)
    const int bh = blockIdx.y;           // b*NH + h
    const int b  = bh / NH_;
    const int h  = bh % NH_;
    const size_t base = (size_t)b * S_ * D_ + (size_t)h * HD_;

    __shared__ float Qs[HD_][68];   // [d][q]  (transposed)
    __shared__ float Ks[HD_][68];   // [d][k]  (transposed)
    __shared__ float Vs[64][68];    // [k][d]
    __shared__ float Ps[64][68];    // [q][k]

    const int tid = threadIdx.x;
    const int tx = tid & 15;
    const int ty = tid >> 4;

    // load Q tile (64 rows x 64 dims), transposed into Qs[d][q]
    {
        const int r  = tid >> 4;          // 0..15
        const int d4 = (tid & 15) * 4;    // 0..60
#pragma unroll
        for (int it = 0; it < 4; ++it) {
            int row = r + 16 * it;
            float4 q4 = *reinterpret_cast<const float4*>(
                &Q[base + (size_t)(qt * 64 + row) * D_ + d4]);
            Qs[d4 + 0][row] = q4.x; Qs[d4 + 1][row] = q4.y;
            Qs[d4 + 2][row] = q4.z; Qs[d4 + 3][row] = q4.w;
        }
    }

    float m_run[4], l_run[4];
    float oacc[4][4] = {};
#pragma unroll
    for (int i = 0; i < 4; ++i) { m_run[i] = -1e30f; l_run[i] = 0.f; }

    __syncthreads();

    for (int kt = 0; kt < S_ / 64; ++kt) {
        // stage K (transposed) and V (straight) tiles
        {
            const int r  = tid >> 4;
            const int d4 = (tid & 15) * 4;
#pragma unroll
            for (int it = 0; it < 4; ++it) {
                int row = r + 16 * it;
                float4 k4 = *reinterpret_cast<const float4*>(
                    &Km[base + (size_t)(kt * 64 + row) * D_ + d4]);
                float4 v4 = *reinterpret_cast<const float4*>(
                    &V[base + (size_t)(kt * 64 + row) * D_ + d4]);
                Ks[d4 + 0][row] = k4.x; Ks[d4 + 1][row] = k4.y;
                Ks[d4 + 2][row] = k4.z; Ks[d4 + 3][row] = k4.w;
                *reinterpret_cast<float4*>(&Vs[row][d4]) = v4;
            }
        }
        __syncthreads();

        // scores tile: s[i][j] = sum_d Qs[d][ty*4+i] * Ks[d][tx*4+j]
        float s[4][4] = {};
#pragma unroll
        for (int d = 0; d < HD_; ++d) {
            float4 qv = *reinterpret_cast<const float4*>(&Qs[d][ty * 4]);
            float4 kv = *reinterpret_cast<const float4*>(&Ks[d][tx * 4]);
            float qr[4] = {qv.x, qv.y, qv.z, qv.w};
            float kr[4] = {kv.x, kv.y, kv.z, kv.w};
#pragma unroll
            for (int i = 0; i < 4; ++i)
#pragma unroll
                for (int j = 0; j < 4; ++j)
                    s[i][j] = fmaf(qr[i], kr[j], s[i][j]);
        }

        // online softmax; row q = qt*64 + ty*4 + i spans 16 lanes (tx)
#pragma unroll
        for (int i = 0; i < 4; ++i) {
#pragma unroll
            for (int j = 0; j < 4; ++j) s[i][j] *= 0.125f;  // 1/sqrt(64)
            float rm = fmaxf(fmaxf(s[i][0], s[i][1]), fmaxf(s[i][2], s[i][3]));
#pragma unroll
            for (int off = 1; off < 16; off <<= 1)
                rm = fmaxf(rm, __shfl_xor(rm, off));
            float mnew = fmaxf(m_run[i], rm);
            float c = __expf(m_run[i] - mnew);
            m_run[i] = mnew;
            float rs = 0.f;
#pragma unroll
            for (int j = 0; j < 4; ++j) {
                s[i][j] = __expf(s[i][j] - mnew);
                rs += s[i][j];
            }
#pragma unroll
            for (int off = 1; off < 16; off <<= 1)
                rs += __shfl_xor(rs, off);
            l_run[i] = l_run[i] * c + rs;
#pragma unroll
            for (int j = 0; j < 4; ++j) oacc[i][j] *= c;
            *reinterpret_cast<float4*>(&Ps[ty * 4 + i][tx * 4]) =
                make_float4(s[i][0], s[i][1], s[i][2], s[i][3]);
        }
        __syncthreads();

        // PV: oacc[i][j] += sum_k Ps[ty*4+i][k] * Vs[k][tx*4+j]
#pragma unroll 8
        for (int k = 0; k < 64; ++k) {
            float4 vv = *reinterpret_cast<const float4*>(&Vs[k][tx * 4]);
#pragma unroll
            for (int i = 0; i < 4; ++i) {
                float p = Ps[ty * 4 + i][k];
                oacc[i][0] = fmaf(p, vv.x, oacc[i][0]);
                oacc[i][1] = fmaf(p, vv.y, oacc[i][1]);
                oacc[i][2] = fmaf(p, vv.z, oacc[i][2]);
                oacc[i][3] = fmaf(p, vv.w, oacc[i][3]);
            }
        }
        __syncthreads();
    }

    // finalize and store: Y[b][qt*64+row][h*64 + d]
#pragma unroll
    for (int i = 0; i < 4; ++i) {
        float inv = 1.0f / l_run[i];
        float4 o = make_float4(oacc[i][0] * inv, oacc[i][1] * inv,
                               oacc[i][2] * inv, oacc[i][3] * inv);
        *reinterpret_cast<float4*>(
            &Y[base + (size_t)(qt * 64 + ty * 4 + i) * D_ + tx * 4]) = o;
    }
}

// ---------------------------------------------------------------------------
extern "C" void kernel_launch(void* const* d_in, const int* in_sizes, int n_in,
                              void* d_out, int out_size, void* d_ws, size_t ws_size,
                              hipStream_t stream) {
    const float* x  = (const float*)d_in[0];
    const float* Wq = (const float*)d_in[1];
    const float* Wk = (const float*)d_in[2];
    const float* Wv = (const float*)d_in[3];
    const float* Wo = (const float*)d_in[4];
    float* out = (float*)d_out;

    const size_t n = (size_t)B_ * S_ * D_;   // 8,388,608 elements
    float* q = (float*)d_ws;
    float* k = q + n;
    float* v = k + n;
    float* y = v + n;

    const int M = B_ * S_;   // 8192
    dim3 blk(256);
    dim3 gproj(D_ / 64, M / 64);    // (16, 128)

    hipLaunchKernelGGL(gemm_bt_f32, gproj, blk, 0, stream, x, Wq, q, M, D_, D_);
    hipLaunchKernelGGL(gemm_bt_f32, gproj, blk, 0, stream, x, Wk, k, M, D_, D_);
    hipLaunchKernelGGL(gemm_bt_f32, gproj, blk, 0, stream, x, Wv, v, M, D_, D_);

    dim3 gattn(S_ / 64, B_ * NH_);  // (32, 64)
    hipLaunchKernelGGL(attn_f32, gattn, blk, 0, stream, q, k, v, y);

    hipLaunchKernelGGL(gemm_bt_f32, gproj, blk, 0, stream, y, Wo, out, M, D_, D_);
}

// Round 2
// 454.204 us; speedup vs baseline: 4.2413x; 4.2413x over previous
//
#include <hip/hip_runtime.h>
#include <hip/hip_bf16.h>

#define B_  4
#define S_  2048
#define D_  1024
#define NH_ 16
#define HD_ 64

typedef __attribute__((ext_vector_type(8))) short bf16x8;
typedef __attribute__((ext_vector_type(4))) float f32x4;

__device__ inline ushort f2bf(float f) {
    uint u = __builtin_bit_cast(uint, f);
    uint r = (u + 0x7fffu + ((u >> 16) & 1u)) >> 16;   // round-to-nearest-even
    return (ushort)r;
}

// ---------------------------------------------------------------------------
// cast f32 -> bf16, 4 elems/thread
// ---------------------------------------------------------------------------
__global__ __launch_bounds__(256) void cast_x(const float* __restrict__ in,
                                              ushort* __restrict__ out, int n) {
    int i = (blockIdx.x * 256 + threadIdx.x) * 4;
    if (i < n) {
        float4 f = *reinterpret_cast<const float4*>(&in[i]);
        ushort4 o = {f2bf(f.x), f2bf(f.y), f2bf(f.z), f2bf(f.w)};
        *reinterpret_cast<ushort4*>(&out[i]) = o;
    }
}

__global__ __launch_bounds__(256) void cast_w4(const float* __restrict__ w0,
                                               const float* __restrict__ w1,
                                               const float* __restrict__ w2,
                                               const float* __restrict__ w3,
                                               ushort* __restrict__ o, int n) {
    const float* src = (blockIdx.y == 0) ? w0 : (blockIdx.y == 1) ? w1
                     : (blockIdx.y == 2) ? w2 : w3;
    ushort* dst = o + (size_t)blockIdx.y * n;
    int i = (blockIdx.x * 256 + threadIdx.x) * 4;
    if (i < n) {
        float4 f = *reinterpret_cast<const float4*>(&src[i]);
        ushort4 v = {f2bf(f.x), f2bf(f.y), f2bf(f.z), f2bf(f.w)};
        *reinterpret_cast<ushort4*>(&dst[i]) = v;
    }
}

// ---------------------------------------------------------------------------
// bf16 MFMA GEMM: C[m,n] = sum_k A[m,k]*W[n,k].  A:[M][K], W:[N][K] bf16.
// 128x128 tile, BK=32, 256 thr (4 waves, each 64x64 = 4x4 frags of 16x16x32).
// m97 structure: global_load_lds width-16 staging, linear LDS.
// ---------------------------------------------------------------------------
template <bool BF16_OUT>
__global__ __launch_bounds__(256) void gemm128(const ushort* __restrict__ A,
                                               const ushort* __restrict__ W,
                                               void* __restrict__ Cv,
                                               int M, int N, int K) {
    __shared__ ushort As[128 * 32];
    __shared__ ushort Ws[128 * 32];
    const int tid = threadIdx.x;
    const int m0 = blockIdx.y * 128;
    const int n0 = blockIdx.x * 128;
    const int lane = tid & 63;
    const int w = tid >> 6;
    const int wr = (w >> 1) * 64;
    const int wc = (w & 1) * 64;
    const int fr = lane & 15;
    const int fq = lane >> 4;

    f32x4 acc[4][4] = {};

    for (int k0 = 0; k0 < K; k0 += 32) {
#pragma unroll
        for (int it = 0; it < 2; ++it) {
            int c = tid + it * 256;            // chunk 0..511 (16B each)
            int row = c >> 2;                  // 0..127
            int col = (c & 3) * 8;
            const ushort* ga = &A[(size_t)(m0 + row) * K + k0 + col];
            const ushort* gw = &W[(size_t)(n0 + row) * K + k0 + col];
            __builtin_amdgcn_global_load_lds(
                (const __attribute__((address_space(1))) uint32_t*)((const void*)ga),
                (__attribute__((address_space(3))) uint32_t*)((void*)&As[c * 8]), 16, 0, 0);
            __builtin_amdgcn_global_load_lds(
                (const __attribute__((address_space(1))) uint32_t*)((const void*)gw),
                (__attribute__((address_space(3))) uint32_t*)((void*)&Ws[c * 8]), 16, 0, 0);
        }
        __syncthreads();

        bf16x8 af[4], bf[4];
#pragma unroll
        for (int m = 0; m < 4; ++m)
            af[m] = *reinterpret_cast<const bf16x8*>(&As[(wr + m * 16 + fr) * 32 + fq * 8]);
#pragma unroll
        for (int n = 0; n < 4; ++n)
            bf[n] = *reinterpret_cast<const bf16x8*>(&Ws[(wc + n * 16 + fr) * 32 + fq * 8]);
#pragma unroll
        for (int m = 0; m < 4; ++m)
#pragma unroll
            for (int n = 0; n < 4; ++n)
                acc[m][n] = __builtin_amdgcn_mfma_f32_16x16x32_bf16(af[m], bf[n], acc[m][n], 0, 0, 0);
        __syncthreads();
    }

    // epilogue: C row = m0+wr+m*16+fq*4+r, col = n0+wc+n*16+fr
#pragma unroll
    for (int m = 0; m < 4; ++m) {
#pragma unroll
        for (int n = 0; n < 4; ++n) {
            int col = n0 + wc + n * 16 + fr;
            int rowb = m0 + wr + m * 16 + fq * 4;
            if (BF16_OUT) {
                ushort* C = (ushort*)Cv;
#pragma unroll
                for (int r = 0; r < 4; ++r)
                    C[(size_t)(rowb + r) * N + col] = f2bf(acc[m][n][r]);
            } else {
                float* C = (float*)Cv;
#pragma unroll
                for (int r = 0; r < 4; ++r)
                    C[(size_t)(rowb + r) * N + col] = acc[m][n][r];
            }
        }
    }
}

// ---------------------------------------------------------------------------
// MFMA flash attention. Block = (128 q-rows, one (b,h)). 4 waves x 32 rows.
// K/V streamed in 64-key tiles; V staged transposed; LDS padded to 72 cols.
// ---------------------------------------------------------------------------
__global__ __launch_bounds__(256) void attn_mfma(const ushort* __restrict__ Qg,
                                                 const ushort* __restrict__ Kg,
                                                 const ushort* __restrict__ Vg,
                                                 ushort* __restrict__ Yg) {
    __shared__ ushort Ks[64 * 72];    // [key][dim]
    __shared__ ushort Vt[64 * 72];    // [dim][key]
    __shared__ ushort Ps[128 * 72];   // Q staging, then P tile [qrow][key]

    const int tid = threadIdx.x;
    const int lane = tid & 63;
    const int w = tid >> 6;
    const int fr = lane & 15;
    const int fq = lane >> 4;
    const int qt = blockIdx.x;
    const int bh = blockIdx.y;
    const int b = bh >> 4;
    const int h = bh & 15;
    const size_t hbase = (size_t)b * (S_ * D_) + (size_t)h * HD_;

    // stage Q tile (128 x 64) into Ps
#pragma unroll
    for (int it = 0; it < 4; ++it) {
        int c = tid + it * 256;           // 0..1023
        int row = c >> 3;
        int ch = (c & 7) * 8;
        bf16x8 v = *reinterpret_cast<const bf16x8*>(
            &Qg[hbase + (size_t)(qt * 128 + row) * D_ + ch]);
        *reinterpret_cast<bf16x8*>(&Ps[row * 72 + ch]) = v;
    }
    __syncthreads();

    bf16x8 qf[2][2];
#pragma unroll
    for (int m = 0; m < 2; ++m)
#pragma unroll
        for (int kk = 0; kk < 2; ++kk)
            qf[m][kk] = *reinterpret_cast<const bf16x8*>(
                &Ps[(w * 32 + m * 16 + fr) * 72 + kk * 32 + fq * 8]);

    float mr[2][4], lr[2][4];
    f32x4 oy[2][4] = {};
#pragma unroll
    for (int m = 0; m < 2; ++m)
#pragma unroll
        for (int r = 0; r < 4; ++r) { mr[m][r] = -1e30f; lr[m][r] = 0.f; }
    __syncthreads();

    for (int kt = 0; kt < S_ / 64; ++kt) {
        // stage K (straight) and V (transposed)
#pragma unroll
        for (int it = 0; it < 2; ++it) {
            int c = tid + it * 256;       // 0..511
            int row = c >> 3;
            int ch = (c & 7) * 8;
            bf16x8 kv = *reinterpret_cast<const bf16x8*>(
                &Kg[hbase + (size_t)(kt * 64 + row) * D_ + ch]);
            *reinterpret_cast<bf16x8*>(&Ks[row * 72 + ch]) = kv;
            bf16x8 vv = *reinterpret_cast<const bf16x8*>(
                &Vg[hbase + (size_t)(kt * 64 + row) * D_ + ch]);
#pragma unroll
            for (int j = 0; j < 8; ++j)
                Vt[(ch + j) * 72 + row] = (ushort)vv[j];
        }
        __syncthreads();

        // QK^T: sc[m][n], rows = q, cols = key
        f32x4 sc[2][4] = {};
#pragma unroll
        for (int kk = 0; kk < 2; ++kk) {
#pragma unroll
            for (int n = 0; n < 4; ++n) {
                bf16x8 kf = *reinterpret_cast<const bf16x8*>(
                    &Ks[(n * 16 + fr) * 72 + kk * 32 + fq * 8]);
                sc[0][n] = __builtin_amdgcn_mfma_f32_16x16x32_bf16(qf[0][kk], kf, sc[0][n], 0, 0, 0);
                sc[1][n] = __builtin_amdgcn_mfma_f32_16x16x32_bf16(qf[1][kk], kf, sc[1][n], 0, 0, 0);
            }
        }

        // online softmax (per q-row: 16 lanes share a row; keys = n*16+fr)
#pragma unroll
        for (int m = 0; m < 2; ++m) {
#pragma unroll
            for (int r = 0; r < 4; ++r) {
                float t0 = sc[m][0][r] * 0.125f;
                float t1 = sc[m][1][r] * 0.125f;
                float t2 = sc[m][2][r] * 0.125f;
                float t3 = sc[m][3][r] * 0.125f;
                float rm = fmaxf(fmaxf(t0, t1), fmaxf(t2, t3));
                rm = fmaxf(rm, __shfl_xor(rm, 1));
                rm = fmaxf(rm, __shfl_xor(rm, 2));
                rm = fmaxf(rm, __shfl_xor(rm, 4));
                rm = fmaxf(rm, __shfl_xor(rm, 8));
                float mnew = fmaxf(mr[m][r], rm);
                float corr = __expf(mr[m][r] - mnew);
                mr[m][r] = mnew;
                float p0 = __expf(t0 - mnew);
                float p1 = __expf(t1 - mnew);
                float p2 = __expf(t2 - mnew);
                float p3 = __expf(t3 - mnew);
                float rs = p0 + p1 + p2 + p3;
                rs += __shfl_xor(rs, 1);
                rs += __shfl_xor(rs, 2);
                rs += __shfl_xor(rs, 4);
                rs += __shfl_xor(rs, 8);
                lr[m][r] = lr[m][r] * corr + rs;
#pragma unroll
                for (int n = 0; n < 4; ++n) oy[m][n][r] *= corr;
                int prow = w * 32 + m * 16 + fq * 4 + r;
                Ps[prow * 72 +  0 + fr] = f2bf(p0);
                Ps[prow * 72 + 16 + fr] = f2bf(p1);
                Ps[prow * 72 + 32 + fr] = f2bf(p2);
                Ps[prow * 72 + 48 + fr] = f2bf(p3);
            }
        }
        __syncthreads();

        // PV: oy[m][n] += P[q][key] * V[key][d]
#pragma unroll
        for (int kk = 0; kk < 2; ++kk) {
            bf16x8 pf0 = *reinterpret_cast<const bf16x8*>(
                &Ps[(w * 32 + 0 + fr) * 72 + kk * 32 + fq * 8]);
            bf16x8 pf1 = *reinterpret_cast<const bf16x8*>(
                &Ps[(w * 32 + 16 + fr) * 72 + kk * 32 + fq * 8]);
#pragma unroll
            for (int n = 0; n < 4; ++n) {
                bf16x8 vf = *reinterpret_cast<const bf16x8*>(
                    &Vt[(n * 16 + fr) * 72 + kk * 32 + fq * 8]);
                oy[0][n] = __builtin_amdgcn_mfma_f32_16x16x32_bf16(pf0, vf, oy[0][n], 0, 0, 0);
                oy[1][n] = __builtin_amdgcn_mfma_f32_16x16x32_bf16(pf1, vf, oy[1][n], 0, 0, 0);
            }
        }
        __syncthreads();
    }

    // epilogue: normalize and store bf16
#pragma unroll
    for (int m = 0; m < 2; ++m) {
#pragma unroll
        for (int r = 0; r < 4; ++r) {
            float inv = 1.0f / lr[m][r];
            int row = qt * 128 + w * 32 + m * 16 + fq * 4 + r;
#pragma unroll
            for (int n = 0; n < 4; ++n)
                Yg[hbase + (size_t)row * D_ + n * 16 + fr] = f2bf(oy[m][n][r] * inv);
        }
    }
}

// ---------------------------------------------------------------------------
extern "C" void kernel_launch(void* const* d_in, const int* in_sizes, int n_in,
                              void* d_out, int out_size, void* d_ws, size_t ws_size,
                              hipStream_t stream) {
    const float* x  = (const float*)d_in[0];
    const float* Wq = (const float*)d_in[1];
    const float* Wk = (const float*)d_in[2];
    const float* Wv = (const float*)d_in[3];
    const float* Wo = (const float*)d_in[4];
    float* out = (float*)d_out;

    const size_t nx = (size_t)B_ * S_ * D_;   // 8,388,608
    const size_t nw = (size_t)D_ * D_;        // 1,048,576

    ushort* xb = (ushort*)d_ws;
    ushort* wb = xb + nx;                     // 4 weights back-to-back
    ushort* qb = wb + 4 * nw;
    ushort* kb = qb + nx;
    ushort* vb = kb + nx;
    ushort* yb = vb + nx;

    dim3 blk(256);
    hipLaunchKernelGGL(cast_x, dim3((nx / 4 + 255) / 256), blk, 0, stream, x, xb, (int)nx);
    hipLaunchKernelGGL(cast_w4, dim3((nw / 4 + 255) / 256, 4), blk, 0, stream,
                       Wq, Wk, Wv, Wo, wb, (int)nw);

    const int M = B_ * S_;                    // 8192
    dim3 gproj(D_ / 128, M / 128);            // (8, 64)
    hipLaunchKernelGGL((gemm128<true>), gproj, blk, 0, stream, xb, wb + 0 * nw, qb, M, D_, D_);
    hipLaunchKernelGGL((gemm128<true>), gproj, blk, 0, stream, xb, wb + 1 * nw, kb, M, D_, D_);
    hipLaunchKernelGGL((gemm128<true>), gproj, blk, 0, stream, xb, wb + 2 * nw, vb, M, D_, D_);

    dim3 gattn(S_ / 128, B_ * NH_);           // (16, 64)
    hipLaunchKernelGGL(attn_mfma, gattn, blk, 0, stream, qb, kb, vb, yb);

    hipLaunchKernelGGL((gemm128<false>), gproj, blk, 0, stream, yb, wb + 3 * nw, out, M, D_, D_);
}

// Round 3
// 304.356 us; speedup vs baseline: 6.3295x; 1.4923x over previous
//
#include <hip/hip_runtime.h>
#include <hip/hip_bf16.h>

#define B_  4
#define S_  2048
#define D_  1024
#define NH_ 16
#define HD_ 64

typedef __attribute__((ext_vector_type(8))) short bf16x8;
typedef __attribute__((ext_vector_type(4))) float f32x4;

__device__ inline ushort f2bf(float f) {
    uint u = __builtin_bit_cast(uint, f);
    uint r = (u + 0x7fffu + ((u >> 16) & 1u)) >> 16;   // round-to-nearest-even
    return (ushort)r;
}

// ---------------------------------------------------------------------------
// cast f32 -> bf16
// ---------------------------------------------------------------------------
__global__ __launch_bounds__(256) void cast_x(const float* __restrict__ in,
                                              ushort* __restrict__ out, int n) {
    int i = (blockIdx.x * 256 + threadIdx.x) * 4;
    if (i < n) {
        float4 f = *reinterpret_cast<const float4*>(&in[i]);
        ushort4 o = {f2bf(f.x), f2bf(f.y), f2bf(f.z), f2bf(f.w)};
        *reinterpret_cast<ushort4*>(&out[i]) = o;
    }
}

__global__ __launch_bounds__(256) void cast_w4(const float* __restrict__ w0,
                                               const float* __restrict__ w1,
                                               const float* __restrict__ w2,
                                               const float* __restrict__ w3,
                                               ushort* __restrict__ o, int n) {
    const float* src = (blockIdx.y == 0) ? w0 : (blockIdx.y == 1) ? w1
                     : (blockIdx.y == 2) ? w2 : w3;
    ushort* dst = o + (size_t)blockIdx.y * n;
    int i = (blockIdx.x * 256 + threadIdx.x) * 4;
    if (i < n) {
        float4 f = *reinterpret_cast<const float4*>(&src[i]);
        ushort4 v = {f2bf(f.x), f2bf(f.y), f2bf(f.z), f2bf(f.w)};
        *reinterpret_cast<ushort4*>(&dst[i]) = v;
    }
}

// ---------------------------------------------------------------------------
// bf16 MFMA GEMM: C[m,n] = sum_k A[m,k]*W[n,k].  128x128 tile, BK=32, 4 waves.
// m97 structure + XCD-aware block swizzle (grid % 8 == 0).
// ---------------------------------------------------------------------------
template <bool BF16_OUT>
__global__ __launch_bounds__(256) void gemm128(const ushort* __restrict__ A,
                                               const ushort* __restrict__ W,
                                               void* __restrict__ Cv,
                                               int M, int N, int K) {
    __shared__ ushort As[128 * 32];
    __shared__ ushort Ws[128 * 32];
    const int tid = threadIdx.x;

    // XCD swizzle: final linear id f -> tile id (f%8)*cpx + f/8
    const int gx = gridDim.x;
    const int nwg = gx * gridDim.y;
    const int f = blockIdx.y * gx + blockIdx.x;
    const int cpx = nwg >> 3;
    const int tileid = (f & 7) * cpx + (f >> 3);
    const int m0 = (tileid / gx) * 128;
    const int n0 = (tileid % gx) * 128;

    const int lane = tid & 63;
    const int w = tid >> 6;
    const int wr = (w >> 1) * 64;
    const int wc = (w & 1) * 64;
    const int fr = lane & 15;
    const int fq = lane >> 4;

    f32x4 acc[4][4] = {};

    for (int k0 = 0; k0 < K; k0 += 32) {
#pragma unroll
        for (int it = 0; it < 2; ++it) {
            int c = tid + it * 256;            // chunk 0..511 (16B each)
            int row = c >> 2;                  // 0..127
            int col = (c & 3) * 8;
            const ushort* ga = &A[(size_t)(m0 + row) * K + k0 + col];
            const ushort* gw = &W[(size_t)(n0 + row) * K + k0 + col];
            __builtin_amdgcn_global_load_lds(
                (const __attribute__((address_space(1))) uint32_t*)((const void*)ga),
                (__attribute__((address_space(3))) uint32_t*)((void*)&As[c * 8]), 16, 0, 0);
            __builtin_amdgcn_global_load_lds(
                (const __attribute__((address_space(1))) uint32_t*)((const void*)gw),
                (__attribute__((address_space(3))) uint32_t*)((void*)&Ws[c * 8]), 16, 0, 0);
        }
        __syncthreads();

        bf16x8 af[4], bfv[4];
#pragma unroll
        for (int m = 0; m < 4; ++m)
            af[m] = *reinterpret_cast<const bf16x8*>(&As[(wr + m * 16 + fr) * 32 + fq * 8]);
#pragma unroll
        for (int n = 0; n < 4; ++n)
            bfv[n] = *reinterpret_cast<const bf16x8*>(&Ws[(wc + n * 16 + fr) * 32 + fq * 8]);
#pragma unroll
        for (int m = 0; m < 4; ++m)
#pragma unroll
            for (int n = 0; n < 4; ++n)
                acc[m][n] = __builtin_amdgcn_mfma_f32_16x16x32_bf16(af[m], bfv[n], acc[m][n], 0, 0, 0);
        __syncthreads();
    }

#pragma unroll
    for (int m = 0; m < 4; ++m) {
#pragma unroll
        for (int n = 0; n < 4; ++n) {
            int col = n0 + wc + n * 16 + fr;
            int rowb = m0 + wr + m * 16 + fq * 4;
            if (BF16_OUT) {
                ushort* C = (ushort*)Cv;
#pragma unroll
                for (int r = 0; r < 4; ++r)
                    C[(size_t)(rowb + r) * N + col] = f2bf(acc[m][n][r]);
            } else {
                float* C = (float*)Cv;
#pragma unroll
                for (int r = 0; r < 4; ++r)
                    C[(size_t)(rowb + r) * N + col] = acc[m][n][r];
            }
        }
    }
}

// ---------------------------------------------------------------------------
// MFMA flash attention, swapped-QK^T. Block = (128 q-rows, one (b,h)).
// 4 waves x 32 q-rows. 64-key tiles. V staged via global column loads ->
// vectorized transposed LDS writes (conflict-free). Reg prefetch of next tile.
// ---------------------------------------------------------------------------
__global__ __launch_bounds__(256) void attn_mfma(const ushort* __restrict__ Qg,
                                                 const ushort* __restrict__ Kg,
                                                 const ushort* __restrict__ Vg,
                                                 ushort* __restrict__ Yg) {
    __shared__ ushort Ks[64 * 72];    // [key][dim]
    __shared__ ushort Vt[64 * 72];    // [dim][key]
    __shared__ ushort Ps[128 * 72];   // Q staging, then P tile [qrow][key]

    const int tid = threadIdx.x;
    const int lane = tid & 63;
    const int w = tid >> 6;
    const int fr = lane & 15;
    const int fq = lane >> 4;
    const int qt = blockIdx.x;
    const int bh = blockIdx.y;
    const int b = bh >> 4;
    const int h = bh & 15;
    const size_t hbase = (size_t)b * (S_ * D_) + (size_t)h * HD_;

    // stage Q tile (128 x 64) into Ps
#pragma unroll
    for (int it = 0; it < 4; ++it) {
        int c = tid + it * 256;           // 0..1023
        int row = c >> 3;
        int ch = (c & 7) * 8;
        bf16x8 v = *reinterpret_cast<const bf16x8*>(
            &Qg[hbase + (size_t)(qt * 128 + row) * D_ + ch]);
        *reinterpret_cast<bf16x8*>(&Ps[row * 72 + ch]) = v;
    }
    __syncthreads();

    bf16x8 qf[2][2];
#pragma unroll
    for (int m = 0; m < 2; ++m)
#pragma unroll
        for (int kk = 0; kk < 2; ++kk)
            qf[m][kk] = *reinterpret_cast<const bf16x8*>(
                &Ps[(w * 32 + m * 16 + fr) * 72 + kk * 32 + fq * 8]);

    float mr[2], lrun[2];
    f32x4 oy[2][4] = {};
    mr[0] = mr[1] = -1e30f;
    lrun[0] = lrun[1] = 0.f;
    __syncthreads();

    // staging-register tiles
    bf16x8 kreg[2];
    ushort vcol[16];
    const int krow0 = tid >> 3;           // rows this thread stages for K
    const int kch = (tid & 7) * 8;

    // prologue: load tile 0
    {
        const ushort* kp = &Kg[hbase + (size_t)(0 + krow0) * D_ + kch];
        kreg[0] = *reinterpret_cast<const bf16x8*>(kp);
        kreg[1] = *reinterpret_cast<const bf16x8*>(kp + (size_t)32 * D_);
        const ushort* vp = &Vg[hbase + (size_t)(0 + w * 16) * D_ + lane];
#pragma unroll
        for (int jj = 0; jj < 16; ++jj)
            vcol[jj] = vp[(size_t)jj * D_];
    }

    const int NT = S_ / 64;
    for (int kt = 0; kt < NT; ++kt) {
        // write staged regs to LDS
        *reinterpret_cast<bf16x8*>(&Ks[krow0 * 72 + kch]) = kreg[0];
        *reinterpret_cast<bf16x8*>(&Ks[(krow0 + 32) * 72 + kch]) = kreg[1];
#pragma unroll
        for (int t = 0; t < 2; ++t)
            *reinterpret_cast<bf16x8*>(&Vt[lane * 72 + w * 16 + t * 8]) =
                *reinterpret_cast<const bf16x8*>(&vcol[t * 8]);
        __syncthreads();

        // QK^T swapped: sc[m][n] = C[key][q],  key=n*16+fq*4+r, q=m*16+fr
        f32x4 sc[2][4] = {};
#pragma unroll
        for (int kk = 0; kk < 2; ++kk) {
#pragma unroll
            for (int n = 0; n < 4; ++n) {
                bf16x8 kf = *reinterpret_cast<const bf16x8*>(
                    &Ks[(n * 16 + fr) * 72 + kk * 32 + fq * 8]);
                sc[0][n] = __builtin_amdgcn_mfma_f32_16x16x32_bf16(kf, qf[0][kk], sc[0][n], 0, 0, 0);
                sc[1][n] = __builtin_amdgcn_mfma_f32_16x16x32_bf16(kf, qf[1][kk], sc[1][n], 0, 0, 0);
            }
        }

        // prefetch next tile K/V into regs (hide global latency under softmax+PV)
        if (kt + 1 < NT) {
            const ushort* kp = &Kg[hbase + (size_t)((kt + 1) * 64 + krow0) * D_ + kch];
            kreg[0] = *reinterpret_cast<const bf16x8*>(kp);
            kreg[1] = *reinterpret_cast<const bf16x8*>(kp + (size_t)32 * D_);
            const ushort* vp = &Vg[hbase + (size_t)((kt + 1) * 64 + w * 16) * D_ + lane];
#pragma unroll
            for (int jj = 0; jj < 16; ++jj)
                vcol[jj] = vp[(size_t)jj * D_];
        }

        // softmax: per lane, q = fr (per m-tile); keys {16n+4fq+r}
#pragma unroll
        for (int m = 0; m < 2; ++m) {
            float pv[4][4];
            float rm = -1e30f;
#pragma unroll
            for (int n = 0; n < 4; ++n)
#pragma unroll
                for (int r = 0; r < 4; ++r) {
                    pv[n][r] = sc[m][n][r] * 0.125f;
                    rm = fmaxf(rm, pv[n][r]);
                }
            rm = fmaxf(rm, __shfl_xor(rm, 16));
            rm = fmaxf(rm, __shfl_xor(rm, 32));
            float mnew = fmaxf(mr[m], rm);
            float corr = __expf(mr[m] - mnew);
            mr[m] = mnew;
            float rs = 0.f;
#pragma unroll
            for (int n = 0; n < 4; ++n)
#pragma unroll
                for (int r = 0; r < 4; ++r) {
                    pv[n][r] = __expf(pv[n][r] - mnew);
                    rs += pv[n][r];
                }
            rs += __shfl_xor(rs, 16);
            rs += __shfl_xor(rs, 32);
            lrun[m] = lrun[m] * corr + rs;

            // rescale oy (its rows live at q = fq*4+r) with broadcast corr
#pragma unroll
            for (int r = 0; r < 4; ++r) {
                float cb = __shfl(corr, fq * 4 + r);
#pragma unroll
                for (int n = 0; n < 4; ++n) oy[m][n][r] *= cb;
            }

            // pack & store P (dword stores, conflict-free)
            const int rowoff = (w * 32 + m * 16 + fr) * 72;
#pragma unroll
            for (int n = 0; n < 4; ++n)
#pragma unroll
                for (int s = 0; s < 2; ++s) {
                    uint pk = (uint)f2bf(pv[n][2 * s]) | ((uint)f2bf(pv[n][2 * s + 1]) << 16);
                    *reinterpret_cast<uint*>(&Ps[rowoff + 16 * n + 4 * fq + 2 * s]) = pk;
                }
        }
        __syncthreads();

        // PV: oy[m][n] += P[q][key] * V[key][d]
#pragma unroll
        for (int kk = 0; kk < 2; ++kk) {
            bf16x8 pf0 = *reinterpret_cast<const bf16x8*>(
                &Ps[(w * 32 + 0 + fr) * 72 + kk * 32 + fq * 8]);
            bf16x8 pf1 = *reinterpret_cast<const bf16x8*>(
                &Ps[(w * 32 + 16 + fr) * 72 + kk * 32 + fq * 8]);
#pragma unroll
            for (int n = 0; n < 4; ++n) {
                bf16x8 vf = *reinterpret_cast<const bf16x8*>(
                    &Vt[(n * 16 + fr) * 72 + kk * 32 + fq * 8]);
                oy[0][n] = __builtin_amdgcn_mfma_f32_16x16x32_bf16(pf0, vf, oy[0][n], 0, 0, 0);
                oy[1][n] = __builtin_amdgcn_mfma_f32_16x16x32_bf16(pf1, vf, oy[1][n], 0, 0, 0);
            }
        }
        __syncthreads();
    }

    // epilogue: normalize (broadcast l to C-row layout) and store bf16
#pragma unroll
    for (int m = 0; m < 2; ++m) {
#pragma unroll
        for (int r = 0; r < 4; ++r) {
            float lb = __shfl(lrun[m], fq * 4 + r);
            float inv = 1.0f / lb;
            int row = qt * 128 + w * 32 + m * 16 + fq * 4 + r;
#pragma unroll
            for (int n = 0; n < 4; ++n)
                Yg[hbase + (size_t)row * D_ + n * 16 + fr] = f2bf(oy[m][n][r] * inv);
        }
    }
}

// ---------------------------------------------------------------------------
extern "C" void kernel_launch(void* const* d_in, const int* in_sizes, int n_in,
                              void* d_out, int out_size, void* d_ws, size_t ws_size,
                              hipStream_t stream) {
    const float* x  = (const float*)d_in[0];
    const float* Wq = (const float*)d_in[1];
    const float* Wk = (const float*)d_in[2];
    const float* Wv = (const float*)d_in[3];
    const float* Wo = (const float*)d_in[4];
    float* out = (float*)d_out;

    const size_t nx = (size_t)B_ * S_ * D_;
    const size_t nw = (size_t)D_ * D_;

    ushort* xb = (ushort*)d_ws;
    ushort* wb = xb + nx;
    ushort* qb = wb + 4 * nw;
    ushort* kb = qb + nx;
    ushort* vb = kb + nx;
    ushort* yb = vb + nx;

    dim3 blk(256);
    hipLaunchKernelGGL(cast_x, dim3((nx / 4 + 255) / 256), blk, 0, stream, x, xb, (int)nx);
    hipLaunchKernelGGL(cast_w4, dim3((nw / 4 + 255) / 256, 4), blk, 0, stream,
                       Wq, Wk, Wv, Wo, wb, (int)nw);

    const int M = B_ * S_;
    dim3 gproj(D_ / 128, M / 128);            // (8, 64) -> 512 blocks, %8==0
    hipLaunchKernelGGL((gemm128<true>), gproj, blk, 0, stream, xb, wb + 0 * nw, qb, M, D_, D_);
    hipLaunchKernelGGL((gemm128<true>), gproj, blk, 0, stream, xb, wb + 1 * nw, kb, M, D_, D_);
    hipLaunchKernelGGL((gemm128<true>), gproj, blk, 0, stream, xb, wb + 2 * nw, vb, M, D_, D_);

    dim3 gattn(S_ / 128, B_ * NH_);           // (16, 64)
    hipLaunchKernelGGL(attn_mfma, gattn, blk, 0, stream, qb, kb, vb, yb);

    hipLaunchKernelGGL((gemm128<false>), gproj, blk, 0, stream, yb, wb + 3 * nw, out, M, D_, D_);
}

// Round 4
// 273.480 us; speedup vs baseline: 7.0441x; 1.1129x over previous
//
#include <hip/hip_runtime.h>
#include <hip/hip_bf16.h>
#include <math.h>

#define B_  4
#define S_  2048
#define D_  1024
#define NH_ 16
#define HD_ 64

typedef __attribute__((ext_vector_type(8))) short bf16x8;
typedef __attribute__((ext_vector_type(4))) float f32x4;
typedef __attribute__((ext_vector_type(4))) uint  u32x4;

__device__ inline ushort f2bf(float f) {
    uint u = __builtin_bit_cast(uint, f);
    uint r = (u + 0x7fffu + ((u >> 16) & 1u)) >> 16;   // RTNE
    return (ushort)r;
}

__device__ inline uint cvt_pk_bf16(float lo, float hi) {
    uint r;
    asm volatile("v_cvt_pk_bf16_f32 %0, %1, %2" : "=v"(r) : "v"(lo), "v"(hi));
    return r;
}

// ---------------------------------------------------------------------------
// cast f32 -> bf16
// ---------------------------------------------------------------------------
__global__ __launch_bounds__(256) void cast_x(const float* __restrict__ in,
                                              ushort* __restrict__ out, int n) {
    int i = (blockIdx.x * 256 + threadIdx.x) * 4;
    if (i < n) {
        float4 f = *reinterpret_cast<const float4*>(&in[i]);
        ushort4 o = {f2bf(f.x), f2bf(f.y), f2bf(f.z), f2bf(f.w)};
        *reinterpret_cast<ushort4*>(&out[i]) = o;
    }
}

__global__ __launch_bounds__(256) void cast_w4(const float* __restrict__ w0,
                                               const float* __restrict__ w1,
                                               const float* __restrict__ w2,
                                               const float* __restrict__ w3,
                                               ushort* __restrict__ o, int n) {
    const float* src = (blockIdx.y == 0) ? w0 : (blockIdx.y == 1) ? w1
                     : (blockIdx.y == 2) ? w2 : w3;
    ushort* dst = o + (size_t)blockIdx.y * n;
    int i = (blockIdx.x * 256 + threadIdx.x) * 4;
    if (i < n) {
        float4 f = *reinterpret_cast<const float4*>(&src[i]);
        ushort4 v = {f2bf(f.x), f2bf(f.y), f2bf(f.z), f2bf(f.w)};
        *reinterpret_cast<ushort4*>(&dst[i]) = v;
    }
}

// ---------------------------------------------------------------------------
// bf16 MFMA GEMM: C[m,n] = sum_k A[m,k]*W[n,k].  128x128 tile, BK=32, 4 waves.
// m97 structure + XCD swizzle. QSCALE folds 0.125*log2(e) into the output
// (used for the Q projection so attention scores land in exp2 domain).
// ---------------------------------------------------------------------------
template <bool BF16_OUT, bool QSCALE>
__global__ __launch_bounds__(256) void gemm128(const ushort* __restrict__ A,
                                               const ushort* __restrict__ W,
                                               void* __restrict__ Cv,
                                               int M, int N, int K) {
    __shared__ ushort As[128 * 32];
    __shared__ ushort Ws[128 * 32];
    const int tid = threadIdx.x;

    const int gx = gridDim.x;
    const int nwg = gx * gridDim.y;
    const int f = blockIdx.y * gx + blockIdx.x;
    const int cpx = nwg >> 3;
    const int tileid = (f & 7) * cpx + (f >> 3);
    const int m0 = (tileid / gx) * 128;
    const int n0 = (tileid % gx) * 128;

    const int lane = tid & 63;
    const int w = tid >> 6;
    const int wr = (w >> 1) * 64;
    const int wc = (w & 1) * 64;
    const int fr = lane & 15;
    const int fq = lane >> 4;

    f32x4 acc[4][4] = {};

    for (int k0 = 0; k0 < K; k0 += 32) {
#pragma unroll
        for (int it = 0; it < 2; ++it) {
            int c = tid + it * 256;
            int row = c >> 2;
            int col = (c & 3) * 8;
            const ushort* ga = &A[(size_t)(m0 + row) * K + k0 + col];
            const ushort* gw = &W[(size_t)(n0 + row) * K + k0 + col];
            __builtin_amdgcn_global_load_lds(
                (const __attribute__((address_space(1))) uint32_t*)((const void*)ga),
                (__attribute__((address_space(3))) uint32_t*)((void*)&As[c * 8]), 16, 0, 0);
            __builtin_amdgcn_global_load_lds(
                (const __attribute__((address_space(1))) uint32_t*)((const void*)gw),
                (__attribute__((address_space(3))) uint32_t*)((void*)&Ws[c * 8]), 16, 0, 0);
        }
        __syncthreads();

        bf16x8 af[4], bfv[4];
#pragma unroll
        for (int m = 0; m < 4; ++m)
            af[m] = *reinterpret_cast<const bf16x8*>(&As[(wr + m * 16 + fr) * 32 + fq * 8]);
#pragma unroll
        for (int n = 0; n < 4; ++n)
            bfv[n] = *reinterpret_cast<const bf16x8*>(&Ws[(wc + n * 16 + fr) * 32 + fq * 8]);
#pragma unroll
        for (int m = 0; m < 4; ++m)
#pragma unroll
            for (int n = 0; n < 4; ++n)
                acc[m][n] = __builtin_amdgcn_mfma_f32_16x16x32_bf16(af[m], bfv[n], acc[m][n], 0, 0, 0);
        __syncthreads();
    }

    const float sc = QSCALE ? 0.18033688011112042f : 1.0f;  // 0.125*log2(e)
#pragma unroll
    for (int m = 0; m < 4; ++m) {
#pragma unroll
        for (int n = 0; n < 4; ++n) {
            int col = n0 + wc + n * 16 + fr;
            int rowb = m0 + wr + m * 16 + fq * 4;
            if (BF16_OUT) {
                ushort* C = (ushort*)Cv;
#pragma unroll
                for (int r = 0; r < 4; ++r)
                    C[(size_t)(rowb + r) * N + col] = f2bf(acc[m][n][r] * sc);
            } else {
                float* C = (float*)Cv;
#pragma unroll
                for (int r = 0; r < 4; ++r)
                    C[(size_t)(rowb + r) * N + col] = acc[m][n][r];
            }
        }
    }
}

// ---------------------------------------------------------------------------
// MFMA flash attention v3: swapped QK^T, P fully in-register (permuted-key
// contraction makes PV A-fragments lane-local), double-buffered K/V LDS
// (1 barrier/tile), exp2-domain softmax, defer-max, setprio on MFMA.
// Block = 128 q-rows of one (b,h); 4 waves x 32 rows; KVBLK = 64.
// ---------------------------------------------------------------------------
__global__ __launch_bounds__(256) void attn_mfma(const ushort* __restrict__ Qg,
                                                 const ushort* __restrict__ Kg,
                                                 const ushort* __restrict__ Vg,
                                                 ushort* __restrict__ Yg) {
    __shared__ ushort Ks[2][64 * 72];   // [key][dim]
    __shared__ ushort Vt[2][64 * 72];   // [dim][c]  (c = permuted key index)

    const int tid = threadIdx.x;
    const int lane = tid & 63;
    const int w = tid >> 6;
    const int fr = lane & 15;
    const int fq = lane >> 4;
    const int qt = blockIdx.x;
    const int bh = blockIdx.y;
    const int b = bh >> 4;
    const int h = bh & 15;
    const size_t hbase = (size_t)b * (S_ * D_) + (size_t)h * HD_;

    // Q fragments directly from global (one-time)
    bf16x8 qf[2][2];
#pragma unroll
    for (int m = 0; m < 2; ++m)
#pragma unroll
        for (int kk = 0; kk < 2; ++kk)
            qf[m][kk] = *reinterpret_cast<const bf16x8*>(
                &Qg[hbase + (size_t)(qt * 128 + w * 32 + m * 16 + fr) * D_ + kk * 32 + fq * 8]);

    float mr[2], lrun[2];
    f32x4 oy[2][4] = {};
    mr[0] = mr[1] = -1e30f;
    lrun[0] = lrun[1] = 0.f;

    // staging registers
    bf16x8 kreg[2];
    ushort vcol[16];
    const int krow0 = tid >> 3;           // 0..31
    const int kch = (tid & 7) * 8;        // 0..56
    const int c0 = w * 16;                // V c-positions this thread covers

    // prologue: load tile 0 into regs
    {
        const ushort* kp = &Kg[hbase + (size_t)krow0 * D_ + kch];
        kreg[0] = *reinterpret_cast<const bf16x8*>(kp);
        kreg[1] = *reinterpret_cast<const bf16x8*>(kp + (size_t)32 * D_);
        const ushort* vp = &Vg[hbase + lane];
#pragma unroll
        for (int jj = 0; jj < 16; ++jj) {
            int c = c0 + jj;
            int key = (c & 32) + ((c >> 3) & 3) * 4 + (c & 3) + ((c >> 2) & 1) * 16;
            vcol[jj] = vp[(size_t)key * D_];
        }
    }

    const int NT = S_ / 64;
    for (int kt = 0; kt < NT; ++kt) {
        const int buf = kt & 1;
        // write staged regs to LDS[buf]
        *reinterpret_cast<bf16x8*>(&Ks[buf][krow0 * 72 + kch]) = kreg[0];
        *reinterpret_cast<bf16x8*>(&Ks[buf][(krow0 + 32) * 72 + kch]) = kreg[1];
#pragma unroll
        for (int t = 0; t < 2; ++t) {
            bf16x8 vv;
#pragma unroll
            for (int j = 0; j < 8; ++j) vv[j] = (short)vcol[t * 8 + j];
            *reinterpret_cast<bf16x8*>(&Vt[buf][lane * 72 + c0 + t * 8]) = vv;
        }
        // prefetch next tile into regs (lands during this tile's compute)
        if (kt + 1 < NT) {
            const ushort* kp = &Kg[hbase + (size_t)((kt + 1) * 64 + krow0) * D_ + kch];
            kreg[0] = *reinterpret_cast<const bf16x8*>(kp);
            kreg[1] = *reinterpret_cast<const bf16x8*>(kp + (size_t)32 * D_);
            const ushort* vp = &Vg[hbase + (size_t)((kt + 1) * 64) * D_ + lane];
#pragma unroll
            for (int jj = 0; jj < 16; ++jj) {
                int c = c0 + jj;
                int key = (c & 32) + ((c >> 3) & 3) * 4 + (c & 3) + ((c >> 2) & 1) * 16;
                vcol[jj] = vp[(size_t)key * D_];
            }
        }
        __syncthreads();

        // QK^T swapped: sc[m][n] = C[key][q]; key = n*16+fq*4+r, q = fr
        f32x4 scv[2][4] = {};
        __builtin_amdgcn_s_setprio(1);
#pragma unroll
        for (int kk = 0; kk < 2; ++kk) {
#pragma unroll
            for (int n = 0; n < 4; ++n) {
                bf16x8 kf = *reinterpret_cast<const bf16x8*>(
                    &Ks[buf][(n * 16 + fr) * 72 + kk * 32 + fq * 8]);
                scv[0][n] = __builtin_amdgcn_mfma_f32_16x16x32_bf16(kf, qf[0][kk], scv[0][n], 0, 0, 0);
                scv[1][n] = __builtin_amdgcn_mfma_f32_16x16x32_bf16(kf, qf[1][kk], scv[1][n], 0, 0, 0);
            }
        }
        __builtin_amdgcn_s_setprio(0);

        // softmax in exp2 domain (scores pre-scaled by 0.125*log2e via Q)
        uint pk[2][4][2];
#pragma unroll
        for (int m = 0; m < 2; ++m) {
            float pmax = -1e30f;
#pragma unroll
            for (int n = 0; n < 4; ++n)
#pragma unroll
                for (int r = 0; r < 4; ++r) pmax = fmaxf(pmax, scv[m][n][r]);
            pmax = fmaxf(pmax, __shfl_xor(pmax, 16));
            pmax = fmaxf(pmax, __shfl_xor(pmax, 32));
            // defer-max: only rescale when some row grew past m+8
            if (!__all(pmax - mr[m] <= 8.f)) {
                float mnew = fmaxf(mr[m], pmax);
                float corr = exp2f(mr[m] - mnew);
                mr[m] = mnew;
                lrun[m] *= corr;
#pragma unroll
                for (int r = 0; r < 4; ++r) {
                    float cb = __shfl(corr, fq * 4 + r);
#pragma unroll
                    for (int n = 0; n < 4; ++n) oy[m][n][r] *= cb;
                }
            }
            float rs = 0.f;
            float pv[4][4];
#pragma unroll
            for (int n = 0; n < 4; ++n)
#pragma unroll
                for (int r = 0; r < 4; ++r) {
                    pv[n][r] = exp2f(scv[m][n][r] - mr[m]);
                    rs += pv[n][r];
                }
            rs += __shfl_xor(rs, 16);
            rs += __shfl_xor(rs, 32);
            lrun[m] += rs;
#pragma unroll
            for (int n = 0; n < 4; ++n) {
                pk[m][n][0] = cvt_pk_bf16(pv[n][0], pv[n][1]);
                pk[m][n][1] = cvt_pk_bf16(pv[n][2], pv[n][3]);
            }
        }

        // PV with permuted-key contraction: pf is lane-local
        __builtin_amdgcn_s_setprio(1);
#pragma unroll
        for (int kk = 0; kk < 2; ++kk) {
            u32x4 a0 = {pk[0][2 * kk][0], pk[0][2 * kk][1], pk[0][2 * kk + 1][0], pk[0][2 * kk + 1][1]};
            u32x4 a1 = {pk[1][2 * kk][0], pk[1][2 * kk][1], pk[1][2 * kk + 1][0], pk[1][2 * kk + 1][1]};
            bf16x8 pf0 = __builtin_bit_cast(bf16x8, a0);
            bf16x8 pf1 = __builtin_bit_cast(bf16x8, a1);
#pragma unroll
            for (int n = 0; n < 4; ++n) {
                bf16x8 vf = *reinterpret_cast<const bf16x8*>(
                    &Vt[buf][(n * 16 + fr) * 72 + kk * 32 + fq * 8]);
                oy[0][n] = __builtin_amdgcn_mfma_f32_16x16x32_bf16(pf0, vf, oy[0][n], 0, 0, 0);
                oy[1][n] = __builtin_amdgcn_mfma_f32_16x16x32_bf16(pf1, vf, oy[1][n], 0, 0, 0);
            }
        }
        __builtin_amdgcn_s_setprio(0);
    }

    // epilogue: normalize and store bf16
#pragma unroll
    for (int m = 0; m < 2; ++m) {
#pragma unroll
        for (int r = 0; r < 4; ++r) {
            float lb = __shfl(lrun[m], fq * 4 + r);
            float inv = 1.0f / lb;
            int row = qt * 128 + w * 32 + m * 16 + fq * 4 + r;
#pragma unroll
            for (int n = 0; n < 4; ++n)
                Yg[hbase + (size_t)row * D_ + n * 16 + fr] = f2bf(oy[m][n][r] * inv);
        }
    }
}

// ---------------------------------------------------------------------------
extern "C" void kernel_launch(void* const* d_in, const int* in_sizes, int n_in,
                              void* d_out, int out_size, void* d_ws, size_t ws_size,
                              hipStream_t stream) {
    const float* x  = (const float*)d_in[0];
    const float* Wq = (const float*)d_in[1];
    const float* Wk = (const float*)d_in[2];
    const float* Wv = (const float*)d_in[3];
    const float* Wo = (const float*)d_in[4];
    float* out = (float*)d_out;

    const size_t nx = (size_t)B_ * S_ * D_;
    const size_t nw = (size_t)D_ * D_;

    ushort* xb = (ushort*)d_ws;
    ushort* wb = xb + nx;
    ushort* qb = wb + 4 * nw;
    ushort* kb = qb + nx;
    ushort* vb = kb + nx;
    ushort* yb = vb + nx;

    dim3 blk(256);
    hipLaunchKernelGGL(cast_x, dim3((nx / 4 + 255) / 256), blk, 0, stream, x, xb, (int)nx);
    hipLaunchKernelGGL(cast_w4, dim3((nw / 4 + 255) / 256, 4), blk, 0, stream,
                       Wq, Wk, Wv, Wo, wb, (int)nw);

    const int M = B_ * S_;
    dim3 gproj(D_ / 128, M / 128);            // (8, 64) -> 512 blocks, %8==0
    hipLaunchKernelGGL((gemm128<true, true >), gproj, blk, 0, stream, xb, wb + 0 * nw, qb, M, D_, D_);
    hipLaunchKernelGGL((gemm128<true, false>), gproj, blk, 0, stream, xb, wb + 1 * nw, kb, M, D_, D_);
    hipLaunchKernelGGL((gemm128<true, false>), gproj, blk, 0, stream, xb, wb + 2 * nw, vb, M, D_, D_);

    dim3 gattn(S_ / 128, B_ * NH_);           // (16, 64)
    hipLaunchKernelGGL(attn_mfma, gattn, blk, 0, stream, qb, kb, vb, yb);

    hipLaunchKernelGGL((gemm128<false, false>), gproj, blk, 0, stream, yb, wb + 3 * nw, out, M, D_, D_);
}

// Round 5
// 272.587 us; speedup vs baseline: 7.0672x; 1.0033x over previous
//
#include <hip/hip_runtime.h>
#include <hip/hip_bf16.h>
#include <math.h>

#define B_  4
#define S_  2048
#define D_  1024
#define NH_ 16
#define HD_ 64

typedef __attribute__((ext_vector_type(8))) short bf16x8;
typedef __attribute__((ext_vector_type(4))) float f32x4;
typedef __attribute__((ext_vector_type(4))) uint  u32x4;

__device__ inline ushort f2bf(float f) {
    uint u = __builtin_bit_cast(uint, f);
    uint r = (u + 0x7fffu + ((u >> 16) & 1u)) >> 16;   // RTNE
    return (ushort)r;
}

__device__ inline uint cvt_pk_bf16(float lo, float hi) {
    uint r;
    asm volatile("v_cvt_pk_bf16_f32 %0, %1, %2" : "=v"(r) : "v"(lo), "v"(hi));
    return r;
}

// ---------------------------------------------------------------------------
// casts
// ---------------------------------------------------------------------------
__global__ __launch_bounds__(256) void cast_x(const float* __restrict__ in,
                                              ushort* __restrict__ out, int n) {
    int i = (blockIdx.x * 256 + threadIdx.x) * 4;
    if (i < n) {
        float4 f = *reinterpret_cast<const float4*>(&in[i]);
        ushort4 o = {f2bf(f.x), f2bf(f.y), f2bf(f.z), f2bf(f.w)};
        *reinterpret_cast<ushort4*>(&out[i]) = o;
    }
}

__global__ __launch_bounds__(256) void cast_w4(const float* __restrict__ w0,
                                               const float* __restrict__ w1,
                                               const float* __restrict__ w2,
                                               const float* __restrict__ w3,
                                               ushort* __restrict__ o, int n) {
    const float* src = (blockIdx.y == 0) ? w0 : (blockIdx.y == 1) ? w1
                     : (blockIdx.y == 2) ? w2 : w3;
    ushort* dst = o + (size_t)blockIdx.y * n;
    int i = (blockIdx.x * 256 + threadIdx.x) * 4;
    if (i < n) {
        float4 f = *reinterpret_cast<const float4*>(&src[i]);
        ushort4 v = {f2bf(f.x), f2bf(f.y), f2bf(f.z), f2bf(f.w)};
        *reinterpret_cast<ushort4*>(&dst[i]) = v;
    }
}

// ---------------------------------------------------------------------------
// bf16 MFMA GEMM, 128x128 tile, BK=32, 4 waves, m97 staging + XCD swizzle.
// MODE 0: fused QKV (W rows = 3072), bf16 out to 3 separate buffers,
//         tensor 0 (Q) scaled by 0.125*log2(e).
// MODE 1: f32 out (out-projection), N = 1024.
// ---------------------------------------------------------------------------
template <int MODE>
__global__ __launch_bounds__(256) void gemm128(const ushort* __restrict__ A,
                                               const ushort* __restrict__ W,
                                               void* __restrict__ Cv,
                                               int M, int Nw, int K) {
    __shared__ ushort As[128 * 32];
    __shared__ ushort Ws[128 * 32];
    const int tid = threadIdx.x;

    const int gx = gridDim.x;
    const int nwg = gx * gridDim.y;
    const int f = blockIdx.y * gx + blockIdx.x;
    const int cpx = nwg >> 3;
    const int tileid = (f & 7) * cpx + (f >> 3);
    const int m0 = (tileid / gx) * 128;
    const int n0 = (tileid % gx) * 128;

    const int lane = tid & 63;
    const int w = tid >> 6;
    const int wr = (w >> 1) * 64;
    const int wc = (w & 1) * 64;
    const int fr = lane & 15;
    const int fq = lane >> 4;

    f32x4 acc[4][4] = {};

    for (int k0 = 0; k0 < K; k0 += 32) {
#pragma unroll
        for (int it = 0; it < 2; ++it) {
            int c = tid + it * 256;
            int row = c >> 2;
            int col = (c & 3) * 8;
            const ushort* ga = &A[(size_t)(m0 + row) * K + k0 + col];
            const ushort* gw = &W[(size_t)(n0 + row) * K + k0 + col];
            __builtin_amdgcn_global_load_lds(
                (const __attribute__((address_space(1))) uint32_t*)((const void*)ga),
                (__attribute__((address_space(3))) uint32_t*)((void*)&As[c * 8]), 16, 0, 0);
            __builtin_amdgcn_global_load_lds(
                (const __attribute__((address_space(1))) uint32_t*)((const void*)gw),
                (__attribute__((address_space(3))) uint32_t*)((void*)&Ws[c * 8]), 16, 0, 0);
        }
        __syncthreads();

        bf16x8 af[4], bfv[4];
#pragma unroll
        for (int m = 0; m < 4; ++m)
            af[m] = *reinterpret_cast<const bf16x8*>(&As[(wr + m * 16 + fr) * 32 + fq * 8]);
#pragma unroll
        for (int n = 0; n < 4; ++n)
            bfv[n] = *reinterpret_cast<const bf16x8*>(&Ws[(wc + n * 16 + fr) * 32 + fq * 8]);
#pragma unroll
        for (int m = 0; m < 4; ++m)
#pragma unroll
            for (int n = 0; n < 4; ++n)
                acc[m][n] = __builtin_amdgcn_mfma_f32_16x16x32_bf16(af[m], bfv[n], acc[m][n], 0, 0, 0);
        __syncthreads();
    }

    if (MODE == 0) {
        const int tensor = n0 >> 10;
        ushort* C = (ushort*)Cv + (size_t)tensor * ((size_t)M * 1024);
        const float sc = (tensor == 0) ? 0.18033688011112042f : 1.0f;  // 0.125*log2e
        const int nb = n0 & 1023;
#pragma unroll
        for (int m = 0; m < 4; ++m)
#pragma unroll
            for (int n = 0; n < 4; ++n) {
                int col = nb + wc + n * 16 + fr;
                int rowb = m0 + wr + m * 16 + fq * 4;
#pragma unroll
                for (int r = 0; r < 4; ++r)
                    C[(size_t)(rowb + r) * 1024 + col] = f2bf(acc[m][n][r] * sc);
            }
    } else {
        float* C = (float*)Cv;
#pragma unroll
        for (int m = 0; m < 4; ++m)
#pragma unroll
            for (int n = 0; n < 4; ++n) {
                int col = n0 + wc + n * 16 + fr;
                int rowb = m0 + wr + m * 16 + fq * 4;
#pragma unroll
                for (int r = 0; r < 4; ++r)
                    C[(size_t)(rowb + r) * Nw + col] = acc[m][n][r];
            }
    }
}

// ---------------------------------------------------------------------------
// MFMA flash attention v4: 3-buffer LDS rotation (1 barrier/tile), loads
// issued AFTER the barrier (whole compute phase to land before next drain),
// K via global_load_lds DMA with pre-swizzled source into XOR-swizzled
// linear [64][64] LDS (conflict-free), same-wave QK^T(t+1) || softmax(t)
// overlap (double sc register set), in-register P, exp2 softmax, defer-max.
// Block = 128 q-rows of one (b,h); 4 waves x 32 rows; KVBLK = 64; NT = 32.
// ---------------------------------------------------------------------------
__global__ __launch_bounds__(256) void attn_mfma(const ushort* __restrict__ Qg,
                                                 const ushort* __restrict__ Kg,
                                                 const ushort* __restrict__ Vg,
                                                 ushort* __restrict__ Yg) {
    __shared__ ushort SH[3 * 8192];   // buf i: K at i*8192, V at i*8192+4096 (48 KB)

    const int tid = threadIdx.x;
    const int lane = tid & 63;
    const int w = tid >> 6;
    const int fr = lane & 15;
    const int fq = lane >> 4;
    const int qt = blockIdx.x;
    const int bh = blockIdx.y;
    const int b = bh >> 4;
    const int h = bh & 15;
    const size_t hbase = (size_t)b * (S_ * D_) + (size_t)h * HD_;
    const int NT = S_ / 64;

    // Q fragments from global (one-time)
    bf16x8 qf[2][2];
#pragma unroll
    for (int m = 0; m < 2; ++m)
#pragma unroll
        for (int kk = 0; kk < 2; ++kk)
            qf[m][kk] = *reinterpret_cast<const bf16x8*>(
                &Qg[hbase + (size_t)(qt * 128 + w * 32 + m * 16 + fr) * D_ + kk * 32 + fq * 8]);

    // precomputed swizzled LDS offsets (elements)
    uint rdoff[2][4];
#pragma unroll
    for (int kk = 0; kk < 2; ++kk)
#pragma unroll
        for (int n = 0; n < 4; ++n)
            rdoff[kk][n] = (uint)((n * 16 + fr) * 64 + 8 * (((kk << 2) + fq) ^ (fr & 7)));
    uint vwoff[2];
#pragma unroll
    for (int t = 0; t < 2; ++t)
        vwoff[t] = (uint)(lane * 64 + 8 * (((w << 1) + t) ^ (lane & 7)));

    // K DMA per-thread constants
    const int c0i = tid, c1i = tid + 256;
    const int krow0 = c0i >> 3, kslot0 = (c0i & 7) ^ (krow0 & 7);
    const int krow1 = c1i >> 3, kslot1 = (c1i & 7) ^ (krow1 & 7);

    float mr[2], lrun[2];
    f32x4 oy[2][4] = {};
    mr[0] = mr[1] = -1e30f;
    lrun[0] = lrun[1] = 0.f;

    ushort vcol[16];

    // ---- lambdas ----
    auto STAGEK = [&](int kt, int bb) {
        const ushort* g0 = &Kg[hbase + (size_t)(kt * 64 + krow0) * D_ + kslot0 * 8];
        const ushort* g1 = &Kg[hbase + (size_t)(kt * 64 + krow1) * D_ + kslot1 * 8];
        __builtin_amdgcn_global_load_lds(
            (const __attribute__((address_space(1))) uint32_t*)((const void*)g0),
            (__attribute__((address_space(3))) uint32_t*)((void*)&SH[bb + c0i * 8]), 16, 0, 0);
        __builtin_amdgcn_global_load_lds(
            (const __attribute__((address_space(1))) uint32_t*)((const void*)g1),
            (__attribute__((address_space(3))) uint32_t*)((void*)&SH[bb + c1i * 8]), 16, 0, 0);
    };
    auto VLOAD = [&](int kt) {
        const ushort* vp = &Vg[hbase + (size_t)(kt * 64) * D_ + lane];
#pragma unroll
        for (int jj = 0; jj < 16; ++jj) {
            int c = w * 16 + jj;
            int key = (c & 32) + ((c >> 3) & 3) * 4 + (c & 3) + ((c >> 2) & 1) * 16;
            vcol[jj] = vp[(size_t)key * D_];
        }
    };
    auto VWRITE = [&](int bb) {
#pragma unroll
        for (int t = 0; t < 2; ++t) {
            bf16x8 vv;
#pragma unroll
            for (int j = 0; j < 8; ++j) vv[j] = (short)vcol[t * 8 + j];
            *reinterpret_cast<bf16x8*>(&SH[bb + 4096 + vwoff[t]]) = vv;
        }
    };
    auto QKT = [&](f32x4 (&sc)[2][4], int bb) {
#pragma unroll
        for (int m = 0; m < 2; ++m)
#pragma unroll
            for (int n = 0; n < 4; ++n) sc[m][n] = f32x4{0.f, 0.f, 0.f, 0.f};
        __builtin_amdgcn_s_setprio(1);
#pragma unroll
        for (int kk = 0; kk < 2; ++kk)
#pragma unroll
            for (int n = 0; n < 4; ++n) {
                bf16x8 kf = *reinterpret_cast<const bf16x8*>(&SH[bb + rdoff[kk][n]]);
                sc[0][n] = __builtin_amdgcn_mfma_f32_16x16x32_bf16(kf, qf[0][kk], sc[0][n], 0, 0, 0);
                sc[1][n] = __builtin_amdgcn_mfma_f32_16x16x32_bf16(kf, qf[1][kk], sc[1][n], 0, 0, 0);
            }
        __builtin_amdgcn_s_setprio(0);
    };
    auto SMPV = [&](f32x4 (&sc)[2][4], int bb) {
        uint pk[2][4][2];
#pragma unroll
        for (int m = 0; m < 2; ++m) {
            float v[16];
#pragma unroll
            for (int n = 0; n < 4; ++n)
#pragma unroll
                for (int r = 0; r < 4; ++r) v[n * 4 + r] = sc[m][n][r];
            // tree max
            float t8[8];
#pragma unroll
            for (int i = 0; i < 8; ++i) t8[i] = fmaxf(v[i], v[i + 8]);
            float t4a = fmaxf(t8[0], t8[4]), t4b = fmaxf(t8[1], t8[5]);
            float t4c = fmaxf(t8[2], t8[6]), t4d = fmaxf(t8[3], t8[7]);
            float mx = fmaxf(fmaxf(t4a, t4b), fmaxf(t4c, t4d));
            mx = fmaxf(mx, __shfl_xor(mx, 16));
            mx = fmaxf(mx, __shfl_xor(mx, 32));
            if (!__all(mx - mr[m] <= 8.f)) {
                float mnew = fmaxf(mr[m], mx);
                float corr = exp2f(mr[m] - mnew);
                mr[m] = mnew;
                lrun[m] *= corr;
#pragma unroll
                for (int r = 0; r < 4; ++r) {
                    float cb = __shfl(corr, fq * 4 + r);
#pragma unroll
                    for (int n = 0; n < 4; ++n) oy[m][n][r] *= cb;
                }
            }
            float p[16];
#pragma unroll
            for (int i = 0; i < 16; ++i) p[i] = exp2f(v[i] - mr[m]);
            // tree sum
            float s8[8];
#pragma unroll
            for (int i = 0; i < 8; ++i) s8[i] = p[i] + p[i + 8];
            float s4a = s8[0] + s8[4], s4b = s8[1] + s8[5];
            float s4c = s8[2] + s8[6], s4d = s8[3] + s8[7];
            float rs = (s4a + s4b) + (s4c + s4d);
            rs += __shfl_xor(rs, 16);
            rs += __shfl_xor(rs, 32);
            lrun[m] += rs;
#pragma unroll
            for (int n = 0; n < 4; ++n) {
                pk[m][n][0] = cvt_pk_bf16(p[n * 4 + 0], p[n * 4 + 1]);
                pk[m][n][1] = cvt_pk_bf16(p[n * 4 + 2], p[n * 4 + 3]);
            }
        }
        __builtin_amdgcn_s_setprio(1);
#pragma unroll
        for (int kk = 0; kk < 2; ++kk) {
            u32x4 a0 = {pk[0][2 * kk][0], pk[0][2 * kk][1], pk[0][2 * kk + 1][0], pk[0][2 * kk + 1][1]};
            u32x4 a1 = {pk[1][2 * kk][0], pk[1][2 * kk][1], pk[1][2 * kk + 1][0], pk[1][2 * kk + 1][1]};
            bf16x8 pf0 = __builtin_bit_cast(bf16x8, a0);
            bf16x8 pf1 = __builtin_bit_cast(bf16x8, a1);
#pragma unroll
            for (int n = 0; n < 4; ++n) {
                bf16x8 vf = *reinterpret_cast<const bf16x8*>(&SH[bb + 4096 + rdoff[kk][n]]);
                oy[0][n] = __builtin_amdgcn_mfma_f32_16x16x32_bf16(pf0, vf, oy[0][n], 0, 0, 0);
                oy[1][n] = __builtin_amdgcn_mfma_f32_16x16x32_bf16(pf1, vf, oy[1][n], 0, 0, 0);
            }
        }
        __builtin_amdgcn_s_setprio(0);
    };

    // ---- prologue: K(0),V(0)->b0; K(1),V(1)->b1; vcol=V(2); sc A = QK^T(0)
    int b0 = 0, b1 = 8192, b2 = 16384;
    f32x4 scA[2][4], scB[2][4];
    STAGEK(0, b0);
    STAGEK(1, b1);
    VLOAD(0);
    VWRITE(b0);
    VLOAD(1);
    VWRITE(b1);
    VLOAD(2);
    __syncthreads();
    QKT(scA, b0);

    // ---- main loop, unroll-2 (scA/scB alternate) ----
    for (int t = 0; t < NT; t += 2) {
        // half A: tile t
        __syncthreads();
        if (t + 2 < NT) { VWRITE(b2); STAGEK(t + 2, b2); }
        if (t + 3 < NT) VLOAD(t + 3);
        if (t + 1 < NT) QKT(scB, b1);
        SMPV(scA, b0);
        { int tmp = b0; b0 = b1; b1 = b2; b2 = tmp; }
        // half B: tile t+1
        __syncthreads();
        if (t + 3 < NT) { VWRITE(b2); STAGEK(t + 3, b2); }
        if (t + 4 < NT) VLOAD(t + 4);
        if (t + 2 < NT) QKT(scA, b1);
        SMPV(scB, b0);
        { int tmp = b0; b0 = b1; b1 = b2; b2 = tmp; }
    }

    // ---- epilogue ----
#pragma unroll
    for (int m = 0; m < 2; ++m) {
#pragma unroll
        for (int r = 0; r < 4; ++r) {
            float lb = __shfl(lrun[m], fq * 4 + r);
            float inv = 1.0f / lb;
            int row = qt * 128 + w * 32 + m * 16 + fq * 4 + r;
#pragma unroll
            for (int n = 0; n < 4; ++n)
                Yg[hbase + (size_t)row * D_ + n * 16 + fr] = f2bf(oy[m][n][r] * inv);
        }
    }
}

// ---------------------------------------------------------------------------
extern "C" void kernel_launch(void* const* d_in, const int* in_sizes, int n_in,
                              void* d_out, int out_size, void* d_ws, size_t ws_size,
                              hipStream_t stream) {
    const float* x  = (const float*)d_in[0];
    const float* Wq = (const float*)d_in[1];
    const float* Wk = (const float*)d_in[2];
    const float* Wv = (const float*)d_in[3];
    const float* Wo = (const float*)d_in[4];
    float* out = (float*)d_out;

    const size_t nx = (size_t)B_ * S_ * D_;
    const size_t nw = (size_t)D_ * D_;

    ushort* xb = (ushort*)d_ws;
    ushort* wb = xb + nx;          // Wq,Wk,Wv,Wo contiguous -> [4096][1024]
    ushort* qb = wb + 4 * nw;      // q,k,v contiguous (fused epilogue indexes)
    ushort* kb = qb + nx;
    ushort* vb = kb + nx;
    ushort* yb = vb + nx;

    dim3 blk(256);
    hipLaunchKernelGGL(cast_x, dim3((nx / 4 + 255) / 256), blk, 0, stream, x, xb, (int)nx);
    hipLaunchKernelGGL(cast_w4, dim3((nw / 4 + 255) / 256, 4), blk, 0, stream,
                       Wq, Wk, Wv, Wo, wb, (int)nw);

    const int M = B_ * S_;
    // fused QKV: N = 3072 (Wq,Wk,Wv rows contiguous in wb)
    dim3 gqkv(3072 / 128, M / 128);           // (24, 64) = 1536 blocks, %8==0
    hipLaunchKernelGGL((gemm128<0>), gqkv, blk, 0, stream, xb, wb, qb, M, 3072, D_);

    dim3 gattn(S_ / 128, B_ * NH_);           // (16, 64)
    hipLaunchKernelGGL(attn_mfma, gattn, blk, 0, stream, qb, kb, vb, yb);

    dim3 gproj(D_ / 128, M / 128);            // (8, 64) = 512 blocks
    hipLaunchKernelGGL((gemm128<1>), gproj, blk, 0, stream, yb, wb + 3 * nw, out, M, D_, D_);
}

// Round 6
// 236.355 us; speedup vs baseline: 8.1506x; 1.1533x over previous
//
#include <hip/hip_runtime.h>
#include <hip/hip_bf16.h>
#include <math.h>

#define B_  4
#define S_  2048
#define D_  1024
#define NH_ 16
#define HD_ 64

typedef __attribute__((ext_vector_type(8))) short bf16x8;
typedef __attribute__((ext_vector_type(4))) float f32x4;
typedef __attribute__((ext_vector_type(4))) uint  u32x4;

__device__ inline ushort f2bf(float f) {
    uint u = __builtin_bit_cast(uint, f);
    uint r = (u + 0x7fffu + ((u >> 16) & 1u)) >> 16;   // RTNE
    return (ushort)r;
}

__device__ inline uint cvt_pk_bf16(float lo, float hi) {
    uint r;
    asm volatile("v_cvt_pk_bf16_f32 %0, %1, %2" : "=v"(r) : "v"(lo), "v"(hi));
    return r;
}

// ---------------------------------------------------------------------------
// casts
// ---------------------------------------------------------------------------
__global__ __launch_bounds__(256) void cast_x(const float* __restrict__ in,
                                              ushort* __restrict__ out, int n) {
    int i = (blockIdx.x * 256 + threadIdx.x) * 4;
    if (i < n) {
        float4 f = *reinterpret_cast<const float4*>(&in[i]);
        ushort4 o = {f2bf(f.x), f2bf(f.y), f2bf(f.z), f2bf(f.w)};
        *reinterpret_cast<ushort4*>(&out[i]) = o;
    }
}

__global__ __launch_bounds__(256) void cast_w4(const float* __restrict__ w0,
                                               const float* __restrict__ w1,
                                               const float* __restrict__ w2,
                                               const float* __restrict__ w3,
                                               ushort* __restrict__ o, int n) {
    const float* src = (blockIdx.y == 0) ? w0 : (blockIdx.y == 1) ? w1
                     : (blockIdx.y == 2) ? w2 : w3;
    ushort* dst = o + (size_t)blockIdx.y * n;
    int i = (blockIdx.x * 256 + threadIdx.x) * 4;
    if (i < n) {
        float4 f = *reinterpret_cast<const float4*>(&src[i]);
        ushort4 v = {f2bf(f.x), f2bf(f.y), f2bf(f.z), f2bf(f.w)};
        *reinterpret_cast<ushort4*>(&dst[i]) = v;
    }
}

// ---------------------------------------------------------------------------
// bf16 MFMA GEMM, 128x128 tile, BK=32, 4 waves, m97 staging + XCD swizzle.
// MODE 0: fused QKV (W rows = 3072), bf16 out, tensor 0 scaled by 0.125*log2e.
// MODE 1: f32 out (out-projection).
// ---------------------------------------------------------------------------
template <int MODE>
__global__ __launch_bounds__(256) void gemm128(const ushort* __restrict__ A,
                                               const ushort* __restrict__ W,
                                               void* __restrict__ Cv,
                                               int M, int Nw, int K) {
    __shared__ ushort As[128 * 32];
    __shared__ ushort Ws[128 * 32];
    const int tid = threadIdx.x;

    const int gx = gridDim.x;
    const int nwg = gx * gridDim.y;
    const int f = blockIdx.y * gx + blockIdx.x;
    const int cpx = nwg >> 3;
    const int tileid = (f & 7) * cpx + (f >> 3);
    const int m0 = (tileid / gx) * 128;
    const int n0 = (tileid % gx) * 128;

    const int lane = tid & 63;
    const int w = tid >> 6;
    const int wr = (w >> 1) * 64;
    const int wc = (w & 1) * 64;
    const int fr = lane & 15;
    const int fq = lane >> 4;

    f32x4 acc[4][4] = {};

    for (int k0 = 0; k0 < K; k0 += 32) {
#pragma unroll
        for (int it = 0; it < 2; ++it) {
            int c = tid + it * 256;
            int row = c >> 2;
            int col = (c & 3) * 8;
            const ushort* ga = &A[(size_t)(m0 + row) * K + k0 + col];
            const ushort* gw = &W[(size_t)(n0 + row) * K + k0 + col];
            __builtin_amdgcn_global_load_lds(
                (const __attribute__((address_space(1))) uint32_t*)((const void*)ga),
                (__attribute__((address_space(3))) uint32_t*)((void*)&As[c * 8]), 16, 0, 0);
            __builtin_amdgcn_global_load_lds(
                (const __attribute__((address_space(1))) uint32_t*)((const void*)gw),
                (__attribute__((address_space(3))) uint32_t*)((void*)&Ws[c * 8]), 16, 0, 0);
        }
        __syncthreads();

        bf16x8 af[4], bfv[4];
#pragma unroll
        for (int m = 0; m < 4; ++m)
            af[m] = *reinterpret_cast<const bf16x8*>(&As[(wr + m * 16 + fr) * 32 + fq * 8]);
#pragma unroll
        for (int n = 0; n < 4; ++n)
            bfv[n] = *reinterpret_cast<const bf16x8*>(&Ws[(wc + n * 16 + fr) * 32 + fq * 8]);
#pragma unroll
        for (int m = 0; m < 4; ++m)
#pragma unroll
            for (int n = 0; n < 4; ++n)
                acc[m][n] = __builtin_amdgcn_mfma_f32_16x16x32_bf16(af[m], bfv[n], acc[m][n], 0, 0, 0);
        __syncthreads();
    }

    if (MODE == 0) {
        const int tensor = n0 >> 10;
        ushort* C = (ushort*)Cv + (size_t)tensor * ((size_t)M * 1024);
        const float sc = (tensor == 0) ? 0.18033688011112042f : 1.0f;  // 0.125*log2e
        const int nb = n0 & 1023;
#pragma unroll
        for (int m = 0; m < 4; ++m)
#pragma unroll
            for (int n = 0; n < 4; ++n) {
                int col = nb + wc + n * 16 + fr;
                int rowb = m0 + wr + m * 16 + fq * 4;
#pragma unroll
                for (int r = 0; r < 4; ++r)
                    C[(size_t)(rowb + r) * 1024 + col] = f2bf(acc[m][n][r] * sc);
            }
    } else {
        float* C = (float*)Cv;
#pragma unroll
        for (int m = 0; m < 4; ++m)
#pragma unroll
            for (int n = 0; n < 4; ++n) {
                int col = n0 + wc + n * 16 + fr;
                int rowb = m0 + wr + m * 16 + fq * 4;
#pragma unroll
                for (int r = 0; r < 4; ++r)
                    C[(size_t)(rowb + r) * Nw + col] = acc[m][n][r];
            }
    }
}

// ---------------------------------------------------------------------------
// MFMA flash attention v5: 2-buffer LDS (32 KB -> full 1024-block residency),
// 1 barrier/tile at tile END, staging issued at tile TOP (full compute phase
// to land before the barrier drain). K via global_load_lds DMA with
// pre-swizzled source into XOR-swizzled [64][64] (conflict-free). V via
// permuted column loads packed at load. In-register P, exp2 softmax,
// defer-max, setprio on MFMA clusters.
// Block = 128 q-rows of one (b,h); 4 waves x 32 rows; KVBLK = 64; NT = 32.
// ---------------------------------------------------------------------------
__global__ __launch_bounds__(256, 4) void attn_mfma(const ushort* __restrict__ Qg,
                                                    const ushort* __restrict__ Kg,
                                                    const ushort* __restrict__ Vg,
                                                    ushort* __restrict__ Yg) {
    __shared__ ushort SH[2 * 8192];   // buf b: K at b*8192, V at b*8192+4096

    const int tid = threadIdx.x;
    const int lane = tid & 63;
    const int w = tid >> 6;
    const int fr = lane & 15;
    const int fq = lane >> 4;
    const int qt = blockIdx.x;
    const int bh = blockIdx.y;
    const int b = bh >> 4;
    const int h = bh & 15;
    const size_t hbase = (size_t)b * (S_ * D_) + (size_t)h * HD_;
    const int NT = S_ / 64;

    // Q fragments from global (one-time)
    bf16x8 qf[2][2];
#pragma unroll
    for (int m = 0; m < 2; ++m)
#pragma unroll
        for (int kk = 0; kk < 2; ++kk)
            qf[m][kk] = *reinterpret_cast<const bf16x8*>(
                &Qg[hbase + (size_t)(qt * 128 + w * 32 + m * 16 + fr) * D_ + kk * 32 + fq * 8]);

    // swizzled LDS read offsets (ushort units)
    uint rdoff[2][4];
#pragma unroll
    for (int kk = 0; kk < 2; ++kk)
#pragma unroll
        for (int n = 0; n < 4; ++n)
            rdoff[kk][n] = (uint)((n * 16 + fr) * 64 + 8 * (((kk << 2) + fq) ^ (fr & 7)));
    uint vwoff[2];
#pragma unroll
    for (int t = 0; t < 2; ++t)
        vwoff[t] = (uint)(lane * 64 + 8 * (((w << 1) + t) ^ (lane & 7)));

    // K DMA per-thread constants
    const int c0i = tid, c1i = tid + 256;
    const int krow0 = c0i >> 3, kslot0 = (c0i & 7) ^ (krow0 & 7);
    const int krow1 = c1i >> 3, kslot1 = (c1i & 7) ^ (krow1 & 7);

    float mr[2], lrun[2];
    f32x4 oy[2][4] = {};
    mr[0] = mr[1] = -1e30f;
    lrun[0] = lrun[1] = 0.f;

    uint vpk[8];   // V(t+1) packed pairs

    auto STAGEK = [&](int kt, int bb) {
        const ushort* g0 = &Kg[hbase + (size_t)(kt * 64 + krow0) * D_ + kslot0 * 8];
        const ushort* g1 = &Kg[hbase + (size_t)(kt * 64 + krow1) * D_ + kslot1 * 8];
        __builtin_amdgcn_global_load_lds(
            (const __attribute__((address_space(1))) uint32_t*)((const void*)g0),
            (__attribute__((address_space(3))) uint32_t*)((void*)&SH[bb + c0i * 8]), 16, 0, 0);
        __builtin_amdgcn_global_load_lds(
            (const __attribute__((address_space(1))) uint32_t*)((const void*)g1),
            (__attribute__((address_space(3))) uint32_t*)((void*)&SH[bb + c1i * 8]), 16, 0, 0);
    };
    auto VLOAD = [&](int kt) {
        const ushort* vp = &Vg[hbase + (size_t)(kt * 64) * D_ + lane];
#pragma unroll
        for (int jj = 0; jj < 8; ++jj) {
            int c = w * 16 + jj * 2;
            int key = (c & 32) + ((c >> 3) & 3) * 4 + (c & 3) + ((c >> 2) & 1) * 16;
            uint lo = vp[(size_t)key * D_];
            uint hi = vp[(size_t)(key + 1) * D_];
            vpk[jj] = lo | (hi << 16);
        }
    };
    auto VWRITE = [&](int bb) {
#pragma unroll
        for (int t = 0; t < 2; ++t) {
            u32x4 a = {vpk[t * 4 + 0], vpk[t * 4 + 1], vpk[t * 4 + 2], vpk[t * 4 + 3]};
            *reinterpret_cast<bf16x8*>(&SH[bb + 4096 + vwoff[t]]) =
                __builtin_bit_cast(bf16x8, a);
        }
    };
    auto QKT = [&](f32x4 (&sc)[2][4], int bb) {
#pragma unroll
        for (int m = 0; m < 2; ++m)
#pragma unroll
            for (int n = 0; n < 4; ++n) sc[m][n] = f32x4{0.f, 0.f, 0.f, 0.f};
        __builtin_amdgcn_s_setprio(1);
#pragma unroll
        for (int kk = 0; kk < 2; ++kk)
#pragma unroll
            for (int n = 0; n < 4; ++n) {
                bf16x8 kf = *reinterpret_cast<const bf16x8*>(&SH[bb + rdoff[kk][n]]);
                sc[0][n] = __builtin_amdgcn_mfma_f32_16x16x32_bf16(kf, qf[0][kk], sc[0][n], 0, 0, 0);
                sc[1][n] = __builtin_amdgcn_mfma_f32_16x16x32_bf16(kf, qf[1][kk], sc[1][n], 0, 0, 0);
            }
        __builtin_amdgcn_s_setprio(0);
    };
    auto SMPV = [&](f32x4 (&sc)[2][4], int bb) {
        uint pk[2][4][2];
#pragma unroll
        for (int m = 0; m < 2; ++m) {
            float q0 = fmaxf(fmaxf(sc[m][0][0], sc[m][0][1]), fmaxf(sc[m][0][2], sc[m][0][3]));
            float q1 = fmaxf(fmaxf(sc[m][1][0], sc[m][1][1]), fmaxf(sc[m][1][2], sc[m][1][3]));
            float q2 = fmaxf(fmaxf(sc[m][2][0], sc[m][2][1]), fmaxf(sc[m][2][2], sc[m][2][3]));
            float q3 = fmaxf(fmaxf(sc[m][3][0], sc[m][3][1]), fmaxf(sc[m][3][2], sc[m][3][3]));
            float mx = fmaxf(fmaxf(q0, q1), fmaxf(q2, q3));
            mx = fmaxf(mx, __shfl_xor(mx, 16));
            mx = fmaxf(mx, __shfl_xor(mx, 32));
            if (!__all(mx - mr[m] <= 8.f)) {
                float mnew = fmaxf(mr[m], mx);
                float corr = exp2f(mr[m] - mnew);
                mr[m] = mnew;
                lrun[m] *= corr;
#pragma unroll
                for (int r = 0; r < 4; ++r) {
                    float cb = __shfl(corr, fq * 4 + r);
#pragma unroll
                    for (int n = 0; n < 4; ++n) oy[m][n][r] *= cb;
                }
            }
#pragma unroll
            for (int n = 0; n < 4; ++n)
#pragma unroll
                for (int r = 0; r < 4; ++r)
                    sc[m][n][r] = exp2f(sc[m][n][r] - mr[m]);
            float s0 = (sc[m][0][0] + sc[m][0][1]) + (sc[m][0][2] + sc[m][0][3]);
            float s1 = (sc[m][1][0] + sc[m][1][1]) + (sc[m][1][2] + sc[m][1][3]);
            float s2 = (sc[m][2][0] + sc[m][2][1]) + (sc[m][2][2] + sc[m][2][3]);
            float s3 = (sc[m][3][0] + sc[m][3][1]) + (sc[m][3][2] + sc[m][3][3]);
            float rs = (s0 + s1) + (s2 + s3);
            rs += __shfl_xor(rs, 16);
            rs += __shfl_xor(rs, 32);
            lrun[m] += rs;
#pragma unroll
            for (int n = 0; n < 4; ++n) {
                pk[m][n][0] = cvt_pk_bf16(sc[m][n][0], sc[m][n][1]);
                pk[m][n][1] = cvt_pk_bf16(sc[m][n][2], sc[m][n][3]);
            }
        }
        __builtin_amdgcn_s_setprio(1);
#pragma unroll
        for (int kk = 0; kk < 2; ++kk) {
            u32x4 a0 = {pk[0][2 * kk][0], pk[0][2 * kk][1], pk[0][2 * kk + 1][0], pk[0][2 * kk + 1][1]};
            u32x4 a1 = {pk[1][2 * kk][0], pk[1][2 * kk][1], pk[1][2 * kk + 1][0], pk[1][2 * kk + 1][1]};
            bf16x8 pf0 = __builtin_bit_cast(bf16x8, a0);
            bf16x8 pf1 = __builtin_bit_cast(bf16x8, a1);
#pragma unroll
            for (int n = 0; n < 4; ++n) {
                bf16x8 vf = *reinterpret_cast<const bf16x8*>(&SH[bb + 4096 + rdoff[kk][n]]);
                oy[0][n] = __builtin_amdgcn_mfma_f32_16x16x32_bf16(pf0, vf, oy[0][n], 0, 0, 0);
                oy[1][n] = __builtin_amdgcn_mfma_f32_16x16x32_bf16(pf1, vf, oy[1][n], 0, 0, 0);
            }
        }
        __builtin_amdgcn_s_setprio(0);
    };

    // prologue: K0 DMA + V0 -> buf0; vpk = V1
    STAGEK(0, 0);
    VLOAD(0);
    VWRITE(0);
    VLOAD(1);
    __syncthreads();

    f32x4 sc[2][4];
    for (int t = 0; t < NT; ++t) {
        const int bb = (t & 1) * 8192;
        const int bn = 8192 - bb;
        if (t + 1 < NT) STAGEK(t + 1, bn);
        QKT(sc, bb);
        if (t + 1 < NT) VWRITE(bn);
        if (t + 2 < NT) VLOAD(t + 2);
        SMPV(sc, bb);
        if (t + 1 < NT) __syncthreads();
    }

    // epilogue
#pragma unroll
    for (int m = 0; m < 2; ++m) {
#pragma unroll
        for (int r = 0; r < 4; ++r) {
            float lb = __shfl(lrun[m], fq * 4 + r);
            float inv = 1.0f / lb;
            int row = qt * 128 + w * 32 + m * 16 + fq * 4 + r;
#pragma unroll
            for (int n = 0; n < 4; ++n)
                Yg[hbase + (size_t)row * D_ + n * 16 + fr] = f2bf(oy[m][n][r] * inv);
        }
    }
}

// ---------------------------------------------------------------------------
extern "C" void kernel_launch(void* const* d_in, const int* in_sizes, int n_in,
                              void* d_out, int out_size, void* d_ws, size_t ws_size,
                              hipStream_t stream) {
    const float* x  = (const float*)d_in[0];
    const float* Wq = (const float*)d_in[1];
    const float* Wk = (const float*)d_in[2];
    const float* Wv = (const float*)d_in[3];
    const float* Wo = (const float*)d_in[4];
    float* out = (float*)d_out;

    const size_t nx = (size_t)B_ * S_ * D_;
    const size_t nw = (size_t)D_ * D_;

    ushort* xb = (ushort*)d_ws;
    ushort* wb = xb + nx;          // Wq,Wk,Wv,Wo contiguous -> [4096][1024]
    ushort* qb = wb + 4 * nw;      // q,k,v contiguous
    ushort* kb = qb + nx;
    ushort* vb = kb + nx;
    ushort* yb = vb + nx;

    dim3 blk(256);
    hipLaunchKernelGGL(cast_x, dim3((nx / 4 + 255) / 256), blk, 0, stream, x, xb, (int)nx);
    hipLaunchKernelGGL(cast_w4, dim3((nw / 4 + 255) / 256, 4), blk, 0, stream,
                       Wq, Wk, Wv, Wo, wb, (int)nw);

    const int M = B_ * S_;
    dim3 gqkv(3072 / 128, M / 128);           // 1536 blocks, %8==0
    hipLaunchKernelGGL((gemm128<0>), gqkv, blk, 0, stream, xb, wb, qb, M, 3072, D_);

    dim3 gattn(S_ / 128, B_ * NH_);           // (16, 64) = 1024 blocks
    hipLaunchKernelGGL(attn_mfma, gattn, blk, 0, stream, qb, kb, vb, yb);

    dim3 gproj(D_ / 128, M / 128);            // 512 blocks
    hipLaunchKernelGGL((gemm128<1>), gproj, blk, 0, stream, yb, wb + 3 * nw, out, M, D_, D_);
}

// Round 7
// 234.390 us; speedup vs baseline: 8.2189x; 1.0084x over previous
//
#include <hip/hip_runtime.h>
#include <hip/hip_bf16.h>
#include <math.h>

#define B_  4
#define S_  2048
#define D_  1024
#define NH_ 16
#define HD_ 64

typedef __attribute__((ext_vector_type(8))) short bf16x8;
typedef __attribute__((ext_vector_type(4))) float f32x4;
typedef __attribute__((ext_vector_type(4))) uint  u32x4;

#define VMCNT(n)  asm volatile("s_waitcnt vmcnt(" #n ")" ::: "memory")
#define LGKMCNT0  asm volatile("s_waitcnt lgkmcnt(0)" ::: "memory")
#define SCHEDB()  __builtin_amdgcn_sched_barrier(0)
#define BARRIER() __builtin_amdgcn_s_barrier()

__device__ inline ushort f2bf(float f) {
    uint u = __builtin_bit_cast(uint, f);
    uint r = (u + 0x7fffu + ((u >> 16) & 1u)) >> 16;   // RTNE
    return (ushort)r;
}

__device__ inline uint cvt_pk_bf16(float lo, float hi) {
    uint r;
    asm volatile("v_cvt_pk_bf16_f32 %0, %1, %2" : "=v"(r) : "v"(lo), "v"(hi));
    return r;
}

// ---------------------------------------------------------------------------
// casts
// ---------------------------------------------------------------------------
__global__ __launch_bounds__(256) void cast_x(const float* __restrict__ in,
                                              ushort* __restrict__ out, int n) {
    int i = (blockIdx.x * 256 + threadIdx.x) * 4;
    if (i < n) {
        float4 f = *reinterpret_cast<const float4*>(&in[i]);
        ushort4 o = {f2bf(f.x), f2bf(f.y), f2bf(f.z), f2bf(f.w)};
        *reinterpret_cast<ushort4*>(&out[i]) = o;
    }
}

__global__ __launch_bounds__(256) void cast_w4(const float* __restrict__ w0,
                                               const float* __restrict__ w1,
                                               const float* __restrict__ w2,
                                               const float* __restrict__ w3,
                                               ushort* __restrict__ o, int n) {
    const float* src = (blockIdx.y == 0) ? w0 : (blockIdx.y == 1) ? w1
                     : (blockIdx.y == 2) ? w2 : w3;
    ushort* dst = o + (size_t)blockIdx.y * n;
    int i = (blockIdx.x * 256 + threadIdx.x) * 4;
    if (i < n) {
        float4 f = *reinterpret_cast<const float4*>(&src[i]);
        ushort4 v = {f2bf(f.x), f2bf(f.y), f2bf(f.z), f2bf(f.w)};
        *reinterpret_cast<ushort4*>(&dst[i]) = v;
    }
}

// ---------------------------------------------------------------------------
// bf16 MFMA GEMM, 128x128 tile, BK=32, 4 waves, m97 staging + XCD swizzle.
// MODE 0: fused QKV (W rows = 3072), bf16 out, tensor 0 scaled by 0.125*log2e.
// MODE 1: f32 out (out-projection).
// ---------------------------------------------------------------------------
template <int MODE>
__global__ __launch_bounds__(256) void gemm128(const ushort* __restrict__ A,
                                               const ushort* __restrict__ W,
                                               void* __restrict__ Cv,
                                               int M, int Nw, int K) {
    __shared__ ushort As[128 * 32];
    __shared__ ushort Ws[128 * 32];
    const int tid = threadIdx.x;

    const int gx = gridDim.x;
    const int nwg = gx * gridDim.y;
    const int f = blockIdx.y * gx + blockIdx.x;
    const int cpx = nwg >> 3;
    const int tileid = (f & 7) * cpx + (f >> 3);
    const int m0 = (tileid / gx) * 128;
    const int n0 = (tileid % gx) * 128;

    const int lane = tid & 63;
    const int w = tid >> 6;
    const int wr = (w >> 1) * 64;
    const int wc = (w & 1) * 64;
    const int fr = lane & 15;
    const int fq = lane >> 4;

    f32x4 acc[4][4] = {};

    for (int k0 = 0; k0 < K; k0 += 32) {
#pragma unroll
        for (int it = 0; it < 2; ++it) {
            int c = tid + it * 256;
            int row = c >> 2;
            int col = (c & 3) * 8;
            const ushort* ga = &A[(size_t)(m0 + row) * K + k0 + col];
            const ushort* gw = &W[(size_t)(n0 + row) * K + k0 + col];
            __builtin_amdgcn_global_load_lds(
                (const __attribute__((address_space(1))) uint32_t*)((const void*)ga),
                (__attribute__((address_space(3))) uint32_t*)((void*)&As[c * 8]), 16, 0, 0);
            __builtin_amdgcn_global_load_lds(
                (const __attribute__((address_space(1))) uint32_t*)((const void*)gw),
                (__attribute__((address_space(3))) uint32_t*)((void*)&Ws[c * 8]), 16, 0, 0);
        }
        __syncthreads();

        bf16x8 af[4], bfv[4];
#pragma unroll
        for (int m = 0; m < 4; ++m)
            af[m] = *reinterpret_cast<const bf16x8*>(&As[(wr + m * 16 + fr) * 32 + fq * 8]);
#pragma unroll
        for (int n = 0; n < 4; ++n)
            bfv[n] = *reinterpret_cast<const bf16x8*>(&Ws[(wc + n * 16 + fr) * 32 + fq * 8]);
#pragma unroll
        for (int m = 0; m < 4; ++m)
#pragma unroll
            for (int n = 0; n < 4; ++n)
                acc[m][n] = __builtin_amdgcn_mfma_f32_16x16x32_bf16(af[m], bfv[n], acc[m][n], 0, 0, 0);
        __syncthreads();
    }

    if (MODE == 0) {
        const int tensor = n0 >> 10;
        ushort* C = (ushort*)Cv + (size_t)tensor * ((size_t)M * 1024);
        const float sc = (tensor == 0) ? 0.18033688011112042f : 1.0f;  // 0.125*log2e
        const int nb = n0 & 1023;
#pragma unroll
        for (int m = 0; m < 4; ++m)
#pragma unroll
            for (int n = 0; n < 4; ++n) {
                int col = nb + wc + n * 16 + fr;
                int rowb = m0 + wr + m * 16 + fq * 4;
#pragma unroll
                for (int r = 0; r < 4; ++r)
                    C[(size_t)(rowb + r) * 1024 + col] = f2bf(acc[m][n][r] * sc);
            }
    } else {
        float* C = (float*)Cv;
#pragma unroll
        for (int m = 0; m < 4; ++m)
#pragma unroll
            for (int n = 0; n < 4; ++n) {
                int col = n0 + wc + n * 16 + fr;
                int rowb = m0 + wr + m * 16 + fq * 4;
#pragma unroll
                for (int r = 0; r < 4; ++r)
                    C[(size_t)(rowb + r) * Nw + col] = acc[m][n][r];
            }
    }
}

// ---------------------------------------------------------------------------
// MFMA flash attention v6: raw s_barrier + COUNTED vmcnt (T3/T4) -- prefetch
// loads stay in flight across barriers; only the 2 K-DMAs must retire per
// tile (issue order pinned with sched_barrier). XCD bh-grouping: all 16
// q-tiles of a bh on one XCD (per-XCD K/V working set = 4MB = L2).
// 2-buffer swizzled LDS (32KB), in-register P, exp2 softmax, defer-max.
// ---------------------------------------------------------------------------
__global__ __launch_bounds__(256, 4) void attn_mfma(const ushort* __restrict__ Qg,
                                                    const ushort* __restrict__ Kg,
                                                    const ushort* __restrict__ Vg,
                                                    ushort* __restrict__ Yg) {
    __shared__ ushort SH[2 * 8192];   // buf b: K at b*8192, V at b*8192+4096

    const int tid = threadIdx.x;
    const int lane = tid & 63;
    const int w = tid >> 6;
    const int fr = lane & 15;
    const int fq = lane >> 4;

    // XCD grouping: lin%8 selects XCD (round-robin); all qt of a bh share one
    const int lin = blockIdx.x;
    const int qt = (lin >> 3) & 15;
    const int bh = (lin & 7) * 8 + (lin >> 7);
    const int b = bh >> 4;
    const int h = bh & 15;
    const size_t hbase = (size_t)b * (S_ * D_) + (size_t)h * HD_;
    const int NT = S_ / 64;

    // Q fragments from global (one-time)
    bf16x8 qf[2][2];
#pragma unroll
    for (int m = 0; m < 2; ++m)
#pragma unroll
        for (int kk = 0; kk < 2; ++kk)
            qf[m][kk] = *reinterpret_cast<const bf16x8*>(
                &Qg[hbase + (size_t)(qt * 128 + w * 32 + m * 16 + fr) * D_ + kk * 32 + fq * 8]);

    // swizzled LDS read offsets (ushort units)
    uint rdoff[2][4];
#pragma unroll
    for (int kk = 0; kk < 2; ++kk)
#pragma unroll
        for (int n = 0; n < 4; ++n)
            rdoff[kk][n] = (uint)((n * 16 + fr) * 64 + 8 * (((kk << 2) + fq) ^ (fr & 7)));
    uint vwoff[2];
#pragma unroll
    for (int t = 0; t < 2; ++t)
        vwoff[t] = (uint)(lane * 64 + 8 * (((w << 1) + t) ^ (lane & 7)));

    // K DMA per-thread constants
    const int c0i = tid, c1i = tid + 256;
    const int krow0 = c0i >> 3, kslot0 = (c0i & 7) ^ (krow0 & 7);
    const int krow1 = c1i >> 3, kslot1 = (c1i & 7) ^ (krow1 & 7);

    float mr[2], lrun[2];
    f32x4 oy[2][4] = {};
    mr[0] = mr[1] = -1e30f;
    lrun[0] = lrun[1] = 0.f;

    uint vpk[8];   // V(t+1) packed pairs

    auto STAGEK = [&](int kt, int bb) {
        const ushort* g0 = &Kg[hbase + (size_t)(kt * 64 + krow0) * D_ + kslot0 * 8];
        const ushort* g1 = &Kg[hbase + (size_t)(kt * 64 + krow1) * D_ + kslot1 * 8];
        __builtin_amdgcn_global_load_lds(
            (const __attribute__((address_space(1))) uint32_t*)((const void*)g0),
            (__attribute__((address_space(3))) uint32_t*)((void*)&SH[bb + c0i * 8]), 16, 0, 0);
        __builtin_amdgcn_global_load_lds(
            (const __attribute__((address_space(1))) uint32_t*)((const void*)g1),
            (__attribute__((address_space(3))) uint32_t*)((void*)&SH[bb + c1i * 8]), 16, 0, 0);
    };
    auto VLOAD = [&](int kt) {
        const ushort* vp = &Vg[hbase + (size_t)(kt * 64) * D_ + lane];
#pragma unroll
        for (int jj = 0; jj < 8; ++jj) {
            int c = w * 16 + jj * 2;
            int key = (c & 32) + ((c >> 3) & 3) * 4 + (c & 3) + ((c >> 2) & 1) * 16;
            uint lo = vp[(size_t)key * D_];
            uint hi = vp[(size_t)(key + 1) * D_];
            vpk[jj] = lo | (hi << 16);
        }
    };
    auto VWRITE = [&](int bb) {
#pragma unroll
        for (int t = 0; t < 2; ++t) {
            u32x4 a = {vpk[t * 4 + 0], vpk[t * 4 + 1], vpk[t * 4 + 2], vpk[t * 4 + 3]};
            *reinterpret_cast<bf16x8*>(&SH[bb + 4096 + vwoff[t]]) =
                __builtin_bit_cast(bf16x8, a);
        }
    };
    auto QKT = [&](f32x4 (&sc)[2][4], int bb) {
#pragma unroll
        for (int m = 0; m < 2; ++m)
#pragma unroll
            for (int n = 0; n < 4; ++n) sc[m][n] = f32x4{0.f, 0.f, 0.f, 0.f};
        __builtin_amdgcn_s_setprio(1);
#pragma unroll
        for (int kk = 0; kk < 2; ++kk)
#pragma unroll
            for (int n = 0; n < 4; ++n) {
                bf16x8 kf = *reinterpret_cast<const bf16x8*>(&SH[bb + rdoff[kk][n]]);
                sc[0][n] = __builtin_amdgcn_mfma_f32_16x16x32_bf16(kf, qf[0][kk], sc[0][n], 0, 0, 0);
                sc[1][n] = __builtin_amdgcn_mfma_f32_16x16x32_bf16(kf, qf[1][kk], sc[1][n], 0, 0, 0);
            }
        __builtin_amdgcn_s_setprio(0);
    };
    auto SMPV = [&](f32x4 (&sc)[2][4], int bb) {
        uint pk[2][4][2];
#pragma unroll
        for (int m = 0; m < 2; ++m) {
            float q0 = fmaxf(fmaxf(sc[m][0][0], sc[m][0][1]), fmaxf(sc[m][0][2], sc[m][0][3]));
            float q1 = fmaxf(fmaxf(sc[m][1][0], sc[m][1][1]), fmaxf(sc[m][1][2], sc[m][1][3]));
            float q2 = fmaxf(fmaxf(sc[m][2][0], sc[m][2][1]), fmaxf(sc[m][2][2], sc[m][2][3]));
            float q3 = fmaxf(fmaxf(sc[m][3][0], sc[m][3][1]), fmaxf(sc[m][3][2], sc[m][3][3]));
            float mx = fmaxf(fmaxf(q0, q1), fmaxf(q2, q3));
            mx = fmaxf(mx, __shfl_xor(mx, 16));
            mx = fmaxf(mx, __shfl_xor(mx, 32));
            if (!__all(mx - mr[m] <= 8.f)) {
                float mnew = fmaxf(mr[m], mx);
                float corr = exp2f(mr[m] - mnew);
                mr[m] = mnew;
                lrun[m] *= corr;
#pragma unroll
                for (int r = 0; r < 4; ++r) {
                    float cb = __shfl(corr, fq * 4 + r);
#pragma unroll
                    for (int n = 0; n < 4; ++n) oy[m][n][r] *= cb;
                }
            }
#pragma unroll
            for (int n = 0; n < 4; ++n)
#pragma unroll
                for (int r = 0; r < 4; ++r)
                    sc[m][n][r] = exp2f(sc[m][n][r] - mr[m]);
            float s0 = (sc[m][0][0] + sc[m][0][1]) + (sc[m][0][2] + sc[m][0][3]);
            float s1 = (sc[m][1][0] + sc[m][1][1]) + (sc[m][1][2] + sc[m][1][3]);
            float s2 = (sc[m][2][0] + sc[m][2][1]) + (sc[m][2][2] + sc[m][2][3]);
            float s3 = (sc[m][3][0] + sc[m][3][1]) + (sc[m][3][2] + sc[m][3][3]);
            float rs = (s0 + s1) + (s2 + s3);
            rs += __shfl_xor(rs, 16);
            rs += __shfl_xor(rs, 32);
            lrun[m] += rs;
#pragma unroll
            for (int n = 0; n < 4; ++n) {
                pk[m][n][0] = cvt_pk_bf16(sc[m][n][0], sc[m][n][1]);
                pk[m][n][1] = cvt_pk_bf16(sc[m][n][2], sc[m][n][3]);
            }
        }
        __builtin_amdgcn_s_setprio(1);
#pragma unroll
        for (int kk = 0; kk < 2; ++kk) {
            u32x4 a0 = {pk[0][2 * kk][0], pk[0][2 * kk][1], pk[0][2 * kk + 1][0], pk[0][2 * kk + 1][1]};
            u32x4 a1 = {pk[1][2 * kk][0], pk[1][2 * kk][1], pk[1][2 * kk + 1][0], pk[1][2 * kk + 1][1]};
            bf16x8 pf0 = __builtin_bit_cast(bf16x8, a0);
            bf16x8 pf1 = __builtin_bit_cast(bf16x8, a1);
#pragma unroll
            for (int n = 0; n < 4; ++n) {
                bf16x8 vf = *reinterpret_cast<const bf16x8*>(&SH[bb + 4096 + rdoff[kk][n]]);
                oy[0][n] = __builtin_amdgcn_mfma_f32_16x16x32_bf16(pf0, vf, oy[0][n], 0, 0, 0);
                oy[1][n] = __builtin_amdgcn_mfma_f32_16x16x32_bf16(pf1, vf, oy[1][n], 0, 0, 0);
            }
        }
        __builtin_amdgcn_s_setprio(0);
    };

    // ---- prologue: V0->LDS0 (compiler waits reg deps); K0 DMA; V1 loads ----
    VLOAD(0);
    VWRITE(0);
    STAGEK(0, 0);
    SCHEDB();          // pin the 2 DMAs before the V(1) loads (exact FIFO count)
    VLOAD(1);
    VMCNT(16);         // K0 DMA retired; V(1) x16 in flight
    LGKMCNT0;          // V0 ds_write visible
    BARRIER();
    SCHEDB();

    f32x4 sc[2][4];
    // ---- main loop: t = 0 .. NT-3 (full pipeline, constant counts) ----
    for (int t = 0; t < NT - 2; ++t) {
        const int A = (t & 1) * 8192, Bb = 8192 - A;
        STAGEK(t + 1, Bb);
        SCHEDB();                  // DMAs pinned ahead of the V(t+2) loads
        QKT(sc, A);
        VWRITE(Bb);                // compiler waits V(t+1) reg deps (vmcnt(2))
        VLOAD(t + 2);
        SMPV(sc, A);
        VMCNT(16);                 // K-DMA(t+1) retired; V(t+2) x16 in flight
        LGKMCNT0;                  // V(t+1) ds_write visible
        BARRIER();
        SCHEDB();
    }
    // ---- t = NT-2: no V(t+2) prefetch ----
    {
        const int A = ((NT - 2) & 1) * 8192, Bb = 8192 - A;
        STAGEK(NT - 1, Bb);
        SCHEDB();
        QKT(sc, A);
        VWRITE(Bb);
        SMPV(sc, A);
        VMCNT(0);
        LGKMCNT0;
        BARRIER();
        SCHEDB();
    }
    // ---- t = NT-1: tail, no staging ----
    {
        const int A = ((NT - 1) & 1) * 8192;
        QKT(sc, A);
        SMPV(sc, A);
    }

    // epilogue
#pragma unroll
    for (int m = 0; m < 2; ++m) {
#pragma unroll
        for (int r = 0; r < 4; ++r) {
            float lb = __shfl(lrun[m], fq * 4 + r);
            float inv = 1.0f / lb;
            int row = qt * 128 + w * 32 + m * 16 + fq * 4 + r;
#pragma unroll
            for (int n = 0; n < 4; ++n)
                Yg[hbase + (size_t)row * D_ + n * 16 + fr] = f2bf(oy[m][n][r] * inv);
        }
    }
}

// ---------------------------------------------------------------------------
extern "C" void kernel_launch(void* const* d_in, const int* in_sizes, int n_in,
                              void* d_out, int out_size, void* d_ws, size_t ws_size,
                              hipStream_t stream) {
    const float* x  = (const float*)d_in[0];
    const float* Wq = (const float*)d_in[1];
    const float* Wk = (const float*)d_in[2];
    const float* Wv = (const float*)d_in[3];
    const float* Wo = (const float*)d_in[4];
    float* out = (float*)d_out;

    const size_t nx = (size_t)B_ * S_ * D_;
    const size_t nw = (size_t)D_ * D_;

    ushort* xb = (ushort*)d_ws;
    ushort* wb = xb + nx;          // Wq,Wk,Wv,Wo contiguous -> [4096][1024]
    ushort* qb = wb + 4 * nw;      // q,k,v contiguous
    ushort* kb = qb + nx;
    ushort* vb = kb + nx;
    ushort* yb = vb + nx;

    dim3 blk(256);
    hipLaunchKernelGGL(cast_x, dim3((nx / 4 + 255) / 256), blk, 0, stream, x, xb, (int)nx);
    hipLaunchKernelGGL(cast_w4, dim3((nw / 4 + 255) / 256, 4), blk, 0, stream,
                       Wq, Wk, Wv, Wo, wb, (int)nw);

    const int M = B_ * S_;
    dim3 gqkv(3072 / 128, M / 128);           // 1536 blocks, %8==0
    hipLaunchKernelGGL((gemm128<0>), gqkv, blk, 0, stream, xb, wb, qb, M, 3072, D_);

    dim3 gattn(1024);                         // linear; kernel does XCD grouping
    hipLaunchKernelGGL(attn_mfma, gattn, blk, 0, stream, qb, kb, vb, yb);

    dim3 gproj(D_ / 128, M / 128);            // 512 blocks
    hipLaunchKernelGGL((gemm128<1>), gproj, blk, 0, stream, yb, wb + 3 * nw, out, M, D_, D_);
}